// Round 5
// baseline (524.521 us; speedup 1.0000x reference)
//
#include <hip/hip_runtime.h>
#include <cstdint>

#define DEV __device__ __forceinline__

typedef __bf16 bf16x8 __attribute__((ext_vector_type(8)));
typedef float f32x4 __attribute__((ext_vector_type(4)));

DEV uint16_t f2bf(float f) {
  uint32_t u = __float_as_uint(f);
  u += 0x7FFFu + ((u >> 16) & 1u);
  return (uint16_t)(u >> 16);
}
DEV float bf2f(uint16_t h) { return __uint_as_float(((uint32_t)h) << 16); }

DEV void gload16(const void* g, void* l) {
  __builtin_amdgcn_global_load_lds((const __attribute__((address_space(1))) void*)g,
                                   (__attribute__((address_space(3))) void*)l, 16, 0, 0);
}

template <int N> DEV void waitcnt_vm() {
  if constexpr (N == 0) asm volatile("s_waitcnt vmcnt(0)" ::: "memory");
  else if constexpr (N == 4) asm volatile("s_waitcnt vmcnt(4)" ::: "memory");
  else static_assert(N == 0 || N == 4, "unsupported vmcnt");
}

// fast GELU (tanh/sigmoid form): max abs err vs erf-GELU ~3e-3
DEV float gelu_f(float v) {
  float u = v * (0.7978845608f + 0.0356774081f * v * v);
  return v / (1.f + __expf(-2.f * u));
}

// ---------------- LayerNorm over C=768, fp32 in -> bf16 out ----------------
__global__ __launch_bounds__(256) void ln768(const float* __restrict__ x,
                                             const float* __restrict__ w,
                                             const float* __restrict__ b,
                                             uint16_t* __restrict__ out) {
  const size_t row = blockIdx.x;
  const float* xr = x + row * 768;
  const int t = threadIdx.x;
  float v0 = xr[t], v1 = xr[t + 256], v2 = xr[t + 512];
  float s = v0 + v1 + v2;
  float s2 = v0 * v0 + v1 * v1 + v2 * v2;
#pragma unroll
  for (int o = 32; o; o >>= 1) {
    s += __shfl_down(s, o);
    s2 += __shfl_down(s2, o);
  }
  __shared__ float sh[8];
  if ((t & 63) == 0) { sh[t >> 6] = s; sh[4 + (t >> 6)] = s2; }
  __syncthreads();
  s = sh[0] + sh[1] + sh[2] + sh[3];
  s2 = sh[4] + sh[5] + sh[6] + sh[7];
  const float mu = s * (1.f / 768.f);
  const float var = s2 * (1.f / 768.f) - mu * mu;
  const float rstd = rsqrtf(var + 1e-6f);
  uint16_t* orow = out + row * 768;
  orow[t]       = f2bf((v0 - mu) * rstd * w[t] + b[t]);
  orow[t + 256] = f2bf((v1 - mu) * rstd * w[t + 256] + b[t + 256]);
  orow[t + 512] = f2bf((v2 - mu) * rstd * w[t + 512] + b[t + 512]);
}

// ---------------- transpose fp32 [R,Cc] -> bf16 [Cc,R] ----------------
__global__ __launch_bounds__(256) void transpose_f2b(const float* __restrict__ in,
                                                     uint16_t* __restrict__ outp,
                                                     int ldin, int ldout) {
  __shared__ float tile[32][33];
  const int tx = threadIdx.x, ty = threadIdx.y;
  const size_t x = (size_t)blockIdx.x * 32 + tx;
  const size_t y = (size_t)blockIdx.y * 32 + ty;
#pragma unroll
  for (int j = 0; j < 4; ++j) tile[ty + j * 8][tx] = in[(y + j * 8) * ldin + x];
  __syncthreads();
  const size_t x2 = (size_t)blockIdx.y * 32 + tx;
  const size_t y2 = (size_t)blockIdx.x * 32 + ty;
#pragma unroll
  for (int j = 0; j < 4; ++j) outp[(y2 + j * 8) * ldout + x2] = f2bf(tile[tx][ty + j * 8]);
}

// ---------------- transpose bf16 [R,Cc] -> bf16 [Cc,R] ----------------
__global__ __launch_bounds__(256) void transpose_b2b(const uint16_t* __restrict__ in,
                                                     uint16_t* __restrict__ outp,
                                                     int ldin, int ldout) {
  __shared__ uint16_t tile[32][33];
  const int tx = threadIdx.x, ty = threadIdx.y;
  const size_t x = (size_t)blockIdx.x * 32 + tx;
  const size_t y = (size_t)blockIdx.y * 32 + ty;
#pragma unroll
  for (int j = 0; j < 4; ++j) tile[ty + j * 8][tx] = in[(y + j * 8) * ldin + x];
  __syncthreads();
  const size_t x2 = (size_t)blockIdx.y * 32 + tx;
  const size_t y2 = (size_t)blockIdx.x * 32 + ty;
#pragma unroll
  for (int j = 0; j < 4; ++j) outp[(y2 + j * 8) * ldout + x2] = tile[tx][ty + j * 8];
}

// ======== kv_proj TN with gather ========
__global__ __launch_bounds__(256) void kv_tn(const uint16_t* __restrict__ EkT,
                                             const uint16_t* __restrict__ EvT,
                                             const uint16_t* __restrict__ qkv,
                                             float* __restrict__ part) {
  const int bid = blockIdx.x;
  const int wg = (bid & 7) * 96 + (bid >> 3);
  const int inner = wg & 15;
  const int kt = inner & 3, ns = inner >> 2;
  const int rest = wg >> 4;
  const int ct = rest % 12, kvb = rest / 12;
  const int kv = kvb >> 1, b = kvb & 1;
  const int k0 = kt * 64, c0 = ct * 64, nsb = ns * 2048;

  const uint16_t* E = kv ? EvT : EkT;
  const uint16_t* KV = qkv + (size_t)b * 8192 * 2304 + 768 + kv * 768 + c0;
  const int tid = threadIdx.x, wave = tid >> 6, lane = tid & 63;
  const int l16 = lane & 15, lhi = lane >> 4;
  const int wm = wave >> 1, wn = wave & 1;

  f32x4 acc[2][2];
#pragma unroll
  for (int m = 0; m < 2; ++m)
#pragma unroll
    for (int n = 0; n < 2; ++n) acc[m][n] = f32x4{0.f, 0.f, 0.f, 0.f};

  const uint16_t* Eb = E + (size_t)(k0 + wm * 32 + l16) * 8192 + nsb + lhi * 8;
  const uint16_t* KVb = KV + ((size_t)nsb + lhi * 8) * 2304 + wn * 32 + l16;

  for (int n0 = 0; n0 < 2048; n0 += 32) {
    bf16x8 ef[2];
    ef[0] = *(const bf16x8*)(Eb + n0);
    ef[1] = *(const bf16x8*)(Eb + 16 * 8192 + n0);
    bf16x8 vf[2];
#pragma unroll
    for (int nf = 0; nf < 2; ++nf) {
      const uint16_t* p = KVb + (size_t)n0 * 2304 + nf * 16;
      union { bf16x8 v; uint16_t u[8]; } tu;
#pragma unroll
      for (int j = 0; j < 8; ++j) tu.u[j] = p[(size_t)j * 2304];
      vf[nf] = tu.v;
    }
#pragma unroll
    for (int m = 0; m < 2; ++m)
#pragma unroll
      for (int nf = 0; nf < 2; ++nf)
        acc[m][nf] = __builtin_amdgcn_mfma_f32_16x16x32_bf16(ef[m], vf[nf], acc[m][nf], 0, 0, 0);
  }

  float* outp = part + ((size_t)ns * 4 + kvb) * 196608;
#pragma unroll
  for (int m = 0; m < 2; ++m)
#pragma unroll
    for (int nf = 0; nf < 2; ++nf)
#pragma unroll
      for (int r = 0; r < 4; ++r)
        outp[(size_t)(k0 + wm * 32 + m * 16 + lhi * 4 + r) * 768 + c0 + wn * 32 + nf * 16 + l16] =
            acc[m][nf][r];
}

__global__ __launch_bounds__(256) void kv_reduce(const float* __restrict__ part,
                                                 uint16_t* __restrict__ kproj) {
  const int kvb = blockIdx.y;
  const int i = blockIdx.x * 256 + threadIdx.x;
  const float* p = part + (size_t)kvb * 196608 + i;
  float s = p[0] + p[786432] + p[2 * 786432] + p[3 * 786432];
  kproj[(size_t)kvb * 196608 + i] = f2bf(s);
}

// ======== fused attention (unchanged, verified) ========
__global__ __launch_bounds__(256, 3) void attn_fused(
    const uint16_t* __restrict__ qkv, const uint16_t* __restrict__ kproj,
    const uint16_t* __restrict__ vprojT, uint16_t* __restrict__ o) {
  const int bh = blockIdx.y;
  const int b = bh / 12, h = bh % 12;
  const int n0 = blockIdx.x * 64;
  const int tid = threadIdx.x, wave = tid >> 6, lane = tid & 63;
  const int l16 = lane & 15, lhi = lane >> 4;
  const int wm = wave >> 1, wn = wave & 1;

  __shared__ __align__(16) uint16_t sP[64 * 256];
  __shared__ float redm[2][64], reds[2][64], recs[64];

  const uint16_t* Kp = kproj + (size_t)b * 196608 + h * 64;
  const uint16_t* Qp = qkv + ((size_t)b * 8192 + n0) * 2304 + h * 64;
  const uint16_t* Vp = vprojT + ((size_t)b * 768 + h * 64) * 256;

  f32x4 st[8][2];
#pragma unroll
  for (int m = 0; m < 8; ++m)
#pragma unroll
    for (int nf = 0; nf < 2; ++nf) st[m][nf] = f32x4{0.f, 0.f, 0.f, 0.f};
#pragma unroll
  for (int ks = 0; ks < 2; ++ks) {
    bf16x8 kf[8], qf[2];
#pragma unroll
    for (int m = 0; m < 8; ++m) {
      const int kvi = wm * 128 + m * 16 + l16;
      kf[m] = *(const bf16x8*)(Kp + (size_t)kvi * 768 + ks * 32 + lhi * 8);
    }
#pragma unroll
    for (int nf = 0; nf < 2; ++nf) {
      const int n = wn * 32 + nf * 16 + l16;
      qf[nf] = *(const bf16x8*)(Qp + (size_t)n * 2304 + ks * 32 + lhi * 8);
    }
#pragma unroll
    for (int m = 0; m < 8; ++m)
#pragma unroll
      for (int nf = 0; nf < 2; ++nf)
        st[m][nf] = __builtin_amdgcn_mfma_f32_16x16x32_bf16(kf[m], qf[nf], st[m][nf], 0, 0, 0);
  }

  float pmax[2] = {-50.f, -50.f};
#pragma unroll
  for (int m = 0; m < 8; ++m)
#pragma unroll
    for (int nf = 0; nf < 2; ++nf)
#pragma unroll
      for (int r = 0; r < 4; ++r) {
        float v = fminf(fmaxf(st[m][nf][r] * 0.125f, -50.f), 50.f);
        st[m][nf][r] = v;
        pmax[nf] = fmaxf(pmax[nf], v);
      }
#pragma unroll
  for (int nf = 0; nf < 2; ++nf) {
    pmax[nf] = fmaxf(pmax[nf], __shfl_xor(pmax[nf], 16));
    pmax[nf] = fmaxf(pmax[nf], __shfl_xor(pmax[nf], 32));
  }
  if (lhi == 0) {
#pragma unroll
    for (int nf = 0; nf < 2; ++nf) redm[wm][wn * 32 + nf * 16 + l16] = pmax[nf];
  }
  __syncthreads();
  float M[2];
#pragma unroll
  for (int nf = 0; nf < 2; ++nf) {
    const int col = wn * 32 + nf * 16 + l16;
    M[nf] = fmaxf(redm[0][col], redm[1][col]);
  }

  float psum[2] = {0.f, 0.f};
#pragma unroll
  for (int m = 0; m < 8; ++m) {
#pragma unroll
    for (int nf = 0; nf < 2; ++nf) {
      float e0 = __expf(st[m][nf][0] - M[nf]);
      float e1 = __expf(st[m][nf][1] - M[nf]);
      float e2 = __expf(st[m][nf][2] - M[nf]);
      float e3 = __expf(st[m][nf][3] - M[nf]);
      psum[nf] += (e0 + e1) + (e2 + e3);
      uint2 pk;
      pk.x = (uint32_t)f2bf(e0) | ((uint32_t)f2bf(e1) << 16);
      pk.y = (uint32_t)f2bf(e2) | ((uint32_t)f2bf(e3) << 16);
      const int n = wn * 32 + nf * 16 + l16;
      const int kvb2 = (wm * 128 + m * 16 + lhi * 4) * 2;
      *(uint2*)((char*)sP + n * 512 + (kvb2 ^ ((n & 7) << 4))) = pk;
    }
  }
#pragma unroll
  for (int nf = 0; nf < 2; ++nf) {
    psum[nf] += __shfl_xor(psum[nf], 16);
    psum[nf] += __shfl_xor(psum[nf], 32);
  }
  if (lhi == 0) {
#pragma unroll
    for (int nf = 0; nf < 2; ++nf) reds[wm][wn * 32 + nf * 16 + l16] = psum[nf];
  }
  __syncthreads();
  if (wm == 0 && lhi == 0) {
#pragma unroll
    for (int nf = 0; nf < 2; ++nf) {
      const int col = wn * 32 + nf * 16 + l16;
      recs[col] = 1.f / (reds[0][col] + reds[1][col]);
    }
  }
  __syncthreads();

  f32x4 pacc[2][2];
#pragma unroll
  for (int mf = 0; mf < 2; ++mf)
#pragma unroll
    for (int nf = 0; nf < 2; ++nf) pacc[mf][nf] = f32x4{0.f, 0.f, 0.f, 0.f};
#pragma unroll
  for (int ks = 0; ks < 8; ++ks) {
    bf16x8 pa[2], vb[2];
#pragma unroll
    for (int mf = 0; mf < 2; ++mf) {
      const int n = wm * 32 + mf * 16 + l16;
      pa[mf] = *(const bf16x8*)((char*)sP + n * 512 + ((ks * 64 + lhi * 16) ^ ((n & 7) << 4)));
    }
#pragma unroll
    for (int nf = 0; nf < 2; ++nf) {
      const int d = wn * 32 + nf * 16 + l16;
      vb[nf] = *(const bf16x8*)(Vp + (size_t)d * 256 + ks * 32 + lhi * 8);
    }
#pragma unroll
    for (int mf = 0; mf < 2; ++mf)
#pragma unroll
      for (int nf = 0; nf < 2; ++nf)
        pacc[mf][nf] = __builtin_amdgcn_mfma_f32_16x16x32_bf16(pa[mf], vb[nf], pacc[mf][nf], 0, 0, 0);
  }
  uint16_t* orow = o + ((size_t)b * 8192 + n0) * 768 + h * 64;
#pragma unroll
  for (int mf = 0; mf < 2; ++mf) {
#pragma unroll
    for (int r = 0; r < 4; ++r) {
      const int n = wm * 32 + mf * 16 + lhi * 4 + r;
      const float inv = recs[n];
#pragma unroll
      for (int nf = 0; nf < 2; ++nf) {
        const int d = wn * 32 + nf * 16 + l16;
        orow[(size_t)n * 768 + d] = f2bf(pacc[mf][nf][r] * inv);
      }
    }
  }
}

// ======== gemm256: 8-phase 256x256 NT GEMM (m201 template, plain HIP) ========
// BK=64, 8 waves (2M x 4N), 2 LDS buffers of A(2 K-half planes)+B(2 planes).
// Per K-tile: 4 phases {ds_read 4/8 x b128; stage 1 unit (2 gload16); barrier;
// setprio(1) 16 MFMA setprio(0); [vmcnt(4) at mh==1]; barrier}. vmcnt never 0
// in main loop. Stage order per tile: A-k0, B-k0, A-k1, B-k1 (drain order).
template <bool OUTBF, bool HASBIAS, bool DOGELU, bool HASRES>
__global__ __launch_bounds__(512, 2) void gemm256(
    const uint16_t* __restrict__ A, const uint16_t* __restrict__ B,
    void* __restrict__ Cbase, const float* __restrict__ bias,
    const float* __restrict__ res, int Kd, int lda, int ldb, int ldc) {
  constexpr int PLANE = 8192;       // 256 rows x 32 cols (one K-half of one operand)
  constexpr int BUF = 4 * PLANE;    // A planes 0,1 + B planes 2,3 = 64 KB
  __shared__ __align__(16) uint16_t lds[2 * BUF];  // 128 KB

  const int nn = gridDim.y;
  const int nwg = gridDim.x * gridDim.y;
  const int bid = blockIdx.y * gridDim.x + blockIdx.x;
  const int q = nwg >> 3, r8 = nwg & 7, xcd = bid & 7, idx = bid >> 3;
  const int wg = (xcd < r8 ? xcd * (q + 1) : r8 * (q + 1) + (xcd - r8) * q) + idx;
  const int bm = wg / nn, bn = wg % nn;
  const int row0 = bm * 256, col0 = bn * 256;

  const int tid = threadIdx.x;
  const int wave = tid >> 6, lane = tid & 63;
  const int wm = wave >> 2, wn = wave & 3;   // 2M x 4N
  const int l16 = lane & 15, lhi = lane >> 4;
  const int srow = tid >> 2, sq = tid & 3;

  // stage one unit (op:0=A,1=B ; K-half kh) of K-tile t into buffer b (2 loads)
  auto stage = [&](int b, int t, int op, int kh) {
    const int k0 = t * 64 + kh * 32;
    const uint16_t* G = op ? B : A;
    const int ld = op ? ldb : lda;
    const int r0 = op ? col0 : row0;
    uint16_t* dst = lds + b * BUF + op * 2 * PLANE + kh * PLANE;
#pragma unroll
    for (int j = 0; j < 2; ++j) {
      const int rw = j * 128 + srow;
      const int sl = sq ^ ((rw >> 1) & 3);  // pre-swizzled global slot
      gload16(G + (size_t)(r0 + rw) * ld + k0 + sl * 8, dst + rw * 32 + sq * 8);
    }
  };
  auto rdA = [&](const uint16_t* buf, int ks, int mh, int m) -> bf16x8 {
    const int rw = wm * 128 + mh * 64 + m * 16 + l16;
    const int sl = lhi ^ ((rw >> 1) & 3);
    return *(const bf16x8*)(buf + ks * PLANE + rw * 32 + sl * 8);
  };
  auto rdB = [&](const uint16_t* buf, int ks, int n) -> bf16x8 {
    const int rw = wn * 64 + n * 16 + l16;
    const int sl = lhi ^ ((rw >> 1) & 3);
    return *(const bf16x8*)(buf + 2 * PLANE + ks * PLANE + rw * 32 + sl * 8);
  };

  f32x4 acc[8][4];
#pragma unroll
  for (int m = 0; m < 8; ++m)
#pragma unroll
    for (int n = 0; n < 4; ++n) acc[m][n] = f32x4{0.f, 0.f, 0.f, 0.f};

  const int NT = Kd >> 6;
  // prologue: stage tile 0 in drain order, certify first half
  stage(0, 0, 0, 0); stage(0, 0, 1, 0); stage(0, 0, 0, 1); stage(0, 0, 1, 1);
  waitcnt_vm<4>();
  __builtin_amdgcn_s_barrier();
  asm volatile("" ::: "memory");

  for (int u = 0; u < NT; ++u) {
    const uint16_t* cb = lds + (u & 1) * BUF;
    const int nb = (u + 1) & 1;
    const bool st = (u + 1) < NT;
    bf16x8 bfr[4], afr[4];
#pragma unroll
    for (int ks = 0; ks < 2; ++ks) {
#pragma unroll
      for (int mh = 0; mh < 2; ++mh) {
        if (mh == 0) {
#pragma unroll
          for (int n = 0; n < 4; ++n) bfr[n] = rdB(cb, ks, n);
        }
#pragma unroll
        for (int m = 0; m < 4; ++m) afr[m] = rdA(cb, ks, mh, m);
        if (st) stage(nb, u + 1, mh, ks);  // (ks,mh): (0,0)A-k0 (0,1)B-k0 (1,0)A-k1 (1,1)B-k1
        __builtin_amdgcn_s_barrier();
        asm volatile("" ::: "memory");
        __builtin_amdgcn_s_setprio(1);
#pragma unroll
        for (int m = 0; m < 4; ++m)
#pragma unroll
          for (int n = 0; n < 4; ++n)
            acc[mh * 4 + m][n] =
                __builtin_amdgcn_mfma_f32_16x16x32_bf16(afr[m], bfr[n], acc[mh * 4 + m][n], 0, 0, 0);
        __builtin_amdgcn_s_setprio(0);
        if (mh == 1) {
          if (st) waitcnt_vm<4>();
          else waitcnt_vm<0>();
        }
        __builtin_amdgcn_s_barrier();
        asm volatile("" ::: "memory");
      }
    }
  }

  float* Cf = (float*)Cbase;
  uint16_t* Cb = (uint16_t*)Cbase;
#pragma unroll
  for (int m = 0; m < 8; ++m) {
#pragma unroll
    for (int n = 0; n < 4; ++n) {
      const int col = col0 + wn * 64 + n * 16 + l16;
      float bv = 0.f;
      if (HASBIAS) bv = bias[col];
#pragma unroll
      for (int r = 0; r < 4; ++r) {
        const int row = row0 + wm * 128 + m * 16 + lhi * 4 + r;
        float v = acc[m][n][r] + bv;
        if (DOGELU) v = gelu_f(v);
        const size_t cidx = (size_t)row * ldc + col;
        if (HASRES) v += res[cidx];
        if (OUTBF) Cb[cidx] = f2bf(v);
        else Cf[cidx] = v;
      }
    }
  }
}

extern "C" void kernel_launch(void* const* d_in, const int* in_sizes, int n_in,
                              void* d_out, int out_size, void* d_ws, size_t ws_size,
                              hipStream_t stream) {
  const float* x      = (const float*)d_in[0];
  const float* ln1_w  = (const float*)d_in[1];
  const float* ln1_b  = (const float*)d_in[2];
  const float* qkv_w  = (const float*)d_in[3];
  const float* qkv_b  = (const float*)d_in[4];
  const float* Ek     = (const float*)d_in[5];
  const float* Ev     = (const float*)d_in[6];
  const float* proj_w = (const float*)d_in[7];
  const float* proj_b = (const float*)d_in[8];
  const float* ln2_w  = (const float*)d_in[9];
  const float* ln2_b  = (const float*)d_in[10];
  const float* fc1_w  = (const float*)d_in[11];
  const float* fc1_b  = (const float*)d_in[12];
  const float* fc2_w  = (const float*)d_in[13];
  const float* fc2_b  = (const float*)d_in[14];
  float* out = (float*)d_out;

  char* w8 = (char*)d_ws;
  size_t off = 0;
  auto take = [&](size_t bytes) { char* p = w8 + off; off += bytes; return p; };
  uint16_t* qkv_wT  = (uint16_t*)take(2304ull * 768 * 2);
  uint16_t* proj_wT = (uint16_t*)take(768ull * 768 * 2);
  uint16_t* fc1_wT  = (uint16_t*)take(3072ull * 768 * 2);
  uint16_t* fc2_wT  = (uint16_t*)take(768ull * 3072 * 2);
  uint16_t* EkT     = (uint16_t*)take(256ull * 8192 * 2);
  uint16_t* EvT     = (uint16_t*)take(256ull * 8192 * 2);
  uint16_t* h_bf    = (uint16_t*)take(16384ull * 768 * 2);
  uint16_t* qkv_bf  = (uint16_t*)take(16384ull * 2304 * 2);
  uint16_t* big     = (uint16_t*)take(100663296ull);
  uint16_t* kproj   = (uint16_t*)take(2ull * 2 * 256 * 768 * 2);
  uint16_t* vprojT  = (uint16_t*)take(2ull * 768 * 256 * 2);
  uint16_t* o_bf    = (uint16_t*)take(16384ull * 768 * 2);
  float* part = (float*)big;  // 16 * 196608 * 4B, used before fc1
  (void)ws_size; (void)in_sizes; (void)n_in; (void)out_size;

  const dim3 tb(32, 8);
  // 1) weights / projections -> bf16 transposed (all GEMMs NT)
  transpose_f2b<<<dim3(72, 24), tb, 0, stream>>>(qkv_w, qkv_wT, 2304, 768);
  transpose_f2b<<<dim3(24, 24), tb, 0, stream>>>(proj_w, proj_wT, 768, 768);
  transpose_f2b<<<dim3(96, 24), tb, 0, stream>>>(fc1_w, fc1_wT, 3072, 768);
  transpose_f2b<<<dim3(24, 96), tb, 0, stream>>>(fc2_w, fc2_wT, 768, 3072);
  transpose_f2b<<<dim3(8, 256), tb, 0, stream>>>(Ek, EkT, 256, 8192);
  transpose_f2b<<<dim3(8, 256), tb, 0, stream>>>(Ev, EvT, 256, 8192);
  // 2) LN1
  ln768<<<16384, 256, 0, stream>>>(x, ln1_w, ln1_b, h_bf);
  // 3) qkv = h @ qkv_w + b
  gemm256<true, true, false, false><<<dim3(64, 9), 512, 0, stream>>>(
      h_bf, qkv_wT, qkv_bf, qkv_b, nullptr, 768, 768, 768, 2304);
  // 4) kv_proj: TN gather GEMM, n-split 4 -> fp32 partials, then reduce
  kv_tn<<<768, 256, 0, stream>>>(EkT, EvT, qkv_bf, part);
  kv_reduce<<<dim3(768, 4), 256, 0, stream>>>(part, kproj);
  // 5) v_projT[b] [768,256]
  for (int b = 0; b < 2; ++b)
    transpose_b2b<<<dim3(24, 8), tb, 0, stream>>>(
        kproj + (size_t)(2 + b) * 196608, vprojT + (size_t)b * 768 * 256, 768, 256);
  // 6) fused attention -> o_bf
  attn_fused<<<dim3(128, 24), 256, 0, stream>>>(qkv_bf, kproj, vprojT, o_bf);
  // 7) x2 = x + o @ proj_w + b -> d_out (fp32)
  gemm256<false, true, false, true><<<dim3(64, 3), 512, 0, stream>>>(
      o_bf, proj_wT, out, proj_b, x, 768, 768, 768, 768);
  // 8) LN2
  ln768<<<16384, 256, 0, stream>>>(out, ln2_w, ln2_b, h_bf);
  // 9) a1 = gelu(h2 @ fc1_w + b) -> big
  gemm256<true, true, true, false><<<dim3(64, 12), 512, 0, stream>>>(
      h_bf, fc1_wT, big, fc1_b, nullptr, 768, 768, 768, 3072);
  // 10) out = x2 + a1 @ fc2_w + b (in-place residual)
  gemm256<false, true, false, true><<<dim3(64, 3), 512, 0, stream>>>(
      big, fc2_wT, out, fc2_b, out, 3072, 3072, 3072, 768);
}

// Round 6
// 513.956 us; speedup vs baseline: 1.0206x; 1.0206x over previous
//
#include <hip/hip_runtime.h>
#include <cstdint>

#define DEV __device__ __forceinline__

typedef __bf16 bf16x8 __attribute__((ext_vector_type(8)));
typedef float f32x4 __attribute__((ext_vector_type(4)));

DEV uint16_t f2bf(float f) {
  uint32_t u = __float_as_uint(f);
  u += 0x7FFFu + ((u >> 16) & 1u);
  return (uint16_t)(u >> 16);
}
DEV float bf2f(uint16_t h) { return __uint_as_float(((uint32_t)h) << 16); }

DEV void gload16(const void* g, void* l) {
  __builtin_amdgcn_global_load_lds((const __attribute__((address_space(1))) void*)g,
                                   (__attribute__((address_space(3))) void*)l, 16, 0, 0);
}

template <int N> DEV void waitcnt_vm() {
  if constexpr (N == 0) asm volatile("s_waitcnt vmcnt(0)" ::: "memory");
  else if constexpr (N == 4) asm volatile("s_waitcnt vmcnt(4)" ::: "memory");
  else static_assert(N == 0 || N == 4, "unsupported vmcnt");
}

// fast GELU (tanh/sigmoid form): max abs err vs erf-GELU ~3e-3
DEV float gelu_f(float v) {
  float u = v * (0.7978845608f + 0.0356774081f * v * v);
  return v / (1.f + __expf(-2.f * u));
}

// ---------------- LayerNorm over C=768, fp32 in -> bf16 out ----------------
__global__ __launch_bounds__(256) void ln768(const float* __restrict__ x,
                                             const float* __restrict__ w,
                                             const float* __restrict__ b,
                                             uint16_t* __restrict__ out) {
  const size_t row = blockIdx.x;
  const float* xr = x + row * 768;
  const int t = threadIdx.x;
  float v0 = xr[t], v1 = xr[t + 256], v2 = xr[t + 512];
  float s = v0 + v1 + v2;
  float s2 = v0 * v0 + v1 * v1 + v2 * v2;
#pragma unroll
  for (int o = 32; o; o >>= 1) {
    s += __shfl_down(s, o);
    s2 += __shfl_down(s2, o);
  }
  __shared__ float sh[8];
  if ((t & 63) == 0) { sh[t >> 6] = s; sh[4 + (t >> 6)] = s2; }
  __syncthreads();
  s = sh[0] + sh[1] + sh[2] + sh[3];
  s2 = sh[4] + sh[5] + sh[6] + sh[7];
  const float mu = s * (1.f / 768.f);
  const float var = s2 * (1.f / 768.f) - mu * mu;
  const float rstd = rsqrtf(var + 1e-6f);
  uint16_t* orow = out + row * 768;
  orow[t]       = f2bf((v0 - mu) * rstd * w[t] + b[t]);
  orow[t + 256] = f2bf((v1 - mu) * rstd * w[t + 256] + b[t + 256]);
  orow[t + 512] = f2bf((v2 - mu) * rstd * w[t + 512] + b[t + 512]);
}

// ---------------- transpose fp32 [R,Cc] -> bf16 [Cc,R] ----------------
__global__ __launch_bounds__(256) void transpose_f2b(const float* __restrict__ in,
                                                     uint16_t* __restrict__ outp,
                                                     int ldin, int ldout) {
  __shared__ float tile[32][33];
  const int tx = threadIdx.x, ty = threadIdx.y;
  const size_t x = (size_t)blockIdx.x * 32 + tx;
  const size_t y = (size_t)blockIdx.y * 32 + ty;
#pragma unroll
  for (int j = 0; j < 4; ++j) tile[ty + j * 8][tx] = in[(y + j * 8) * ldin + x];
  __syncthreads();
  const size_t x2 = (size_t)blockIdx.y * 32 + tx;
  const size_t y2 = (size_t)blockIdx.x * 32 + ty;
#pragma unroll
  for (int j = 0; j < 4; ++j) outp[(y2 + j * 8) * ldout + x2] = f2bf(tile[tx][ty + j * 8]);
}

// ---------------- transpose bf16 [R,Cc] -> bf16 [Cc,R] ----------------
__global__ __launch_bounds__(256) void transpose_b2b(const uint16_t* __restrict__ in,
                                                     uint16_t* __restrict__ outp,
                                                     int ldin, int ldout) {
  __shared__ uint16_t tile[32][33];
  const int tx = threadIdx.x, ty = threadIdx.y;
  const size_t x = (size_t)blockIdx.x * 32 + tx;
  const size_t y = (size_t)blockIdx.y * 32 + ty;
#pragma unroll
  for (int j = 0; j < 4; ++j) tile[ty + j * 8][tx] = in[(y + j * 8) * ldin + x];
  __syncthreads();
  const size_t x2 = (size_t)blockIdx.y * 32 + tx;
  const size_t y2 = (size_t)blockIdx.x * 32 + ty;
#pragma unroll
  for (int j = 0; j < 4; ++j) outp[(y2 + j * 8) * ldout + x2] = tile[tx][ty + j * 8];
}

// ======== kv_proj TN with gather ========
__global__ __launch_bounds__(256) void kv_tn(const uint16_t* __restrict__ EkT,
                                             const uint16_t* __restrict__ EvT,
                                             const uint16_t* __restrict__ qkv,
                                             float* __restrict__ part) {
  const int bid = blockIdx.x;
  const int wg = (bid & 7) * 96 + (bid >> 3);
  const int inner = wg & 15;
  const int kt = inner & 3, ns = inner >> 2;
  const int rest = wg >> 4;
  const int ct = rest % 12, kvb = rest / 12;
  const int kv = kvb >> 1, b = kvb & 1;
  const int k0 = kt * 64, c0 = ct * 64, nsb = ns * 2048;

  const uint16_t* E = kv ? EvT : EkT;
  const uint16_t* KV = qkv + (size_t)b * 8192 * 2304 + 768 + kv * 768 + c0;
  const int tid = threadIdx.x, wave = tid >> 6, lane = tid & 63;
  const int l16 = lane & 15, lhi = lane >> 4;
  const int wm = wave >> 1, wn = wave & 1;

  f32x4 acc[2][2];
#pragma unroll
  for (int m = 0; m < 2; ++m)
#pragma unroll
    for (int n = 0; n < 2; ++n) acc[m][n] = f32x4{0.f, 0.f, 0.f, 0.f};

  const uint16_t* Eb = E + (size_t)(k0 + wm * 32 + l16) * 8192 + nsb + lhi * 8;
  const uint16_t* KVb = KV + ((size_t)nsb + lhi * 8) * 2304 + wn * 32 + l16;

  for (int n0 = 0; n0 < 2048; n0 += 32) {
    bf16x8 ef[2];
    ef[0] = *(const bf16x8*)(Eb + n0);
    ef[1] = *(const bf16x8*)(Eb + 16 * 8192 + n0);
    bf16x8 vf[2];
#pragma unroll
    for (int nf = 0; nf < 2; ++nf) {
      const uint16_t* p = KVb + (size_t)n0 * 2304 + nf * 16;
      union { bf16x8 v; uint16_t u[8]; } tu;
#pragma unroll
      for (int j = 0; j < 8; ++j) tu.u[j] = p[(size_t)j * 2304];
      vf[nf] = tu.v;
    }
#pragma unroll
    for (int m = 0; m < 2; ++m)
#pragma unroll
      for (int nf = 0; nf < 2; ++nf)
        acc[m][nf] = __builtin_amdgcn_mfma_f32_16x16x32_bf16(ef[m], vf[nf], acc[m][nf], 0, 0, 0);
  }

  float* outp = part + ((size_t)ns * 4 + kvb) * 196608;
#pragma unroll
  for (int m = 0; m < 2; ++m)
#pragma unroll
    for (int nf = 0; nf < 2; ++nf)
#pragma unroll
      for (int r = 0; r < 4; ++r)
        outp[(size_t)(k0 + wm * 32 + m * 16 + lhi * 4 + r) * 768 + c0 + wn * 32 + nf * 16 + l16] =
            acc[m][nf][r];
}

__global__ __launch_bounds__(256) void kv_reduce(const float* __restrict__ part,
                                                 uint16_t* __restrict__ kproj) {
  const int kvb = blockIdx.y;
  const int i = blockIdx.x * 256 + threadIdx.x;
  const float* p = part + (size_t)kvb * 196608 + i;
  float s = p[0] + p[786432] + p[2 * 786432] + p[3 * 786432];
  kproj[(size_t)kvb * 196608 + i] = f2bf(s);
}

// ======== fused attention (unchanged, verified) ========
__global__ __launch_bounds__(256, 3) void attn_fused(
    const uint16_t* __restrict__ qkv, const uint16_t* __restrict__ kproj,
    const uint16_t* __restrict__ vprojT, uint16_t* __restrict__ o) {
  const int bh = blockIdx.y;
  const int b = bh / 12, h = bh % 12;
  const int n0 = blockIdx.x * 64;
  const int tid = threadIdx.x, wave = tid >> 6, lane = tid & 63;
  const int l16 = lane & 15, lhi = lane >> 4;
  const int wm = wave >> 1, wn = wave & 1;

  __shared__ __align__(16) uint16_t sP[64 * 256];
  __shared__ float redm[2][64], reds[2][64], recs[64];

  const uint16_t* Kp = kproj + (size_t)b * 196608 + h * 64;
  const uint16_t* Qp = qkv + ((size_t)b * 8192 + n0) * 2304 + h * 64;
  const uint16_t* Vp = vprojT + ((size_t)b * 768 + h * 64) * 256;

  f32x4 st[8][2];
#pragma unroll
  for (int m = 0; m < 8; ++m)
#pragma unroll
    for (int nf = 0; nf < 2; ++nf) st[m][nf] = f32x4{0.f, 0.f, 0.f, 0.f};
#pragma unroll
  for (int ks = 0; ks < 2; ++ks) {
    bf16x8 kf[8], qf[2];
#pragma unroll
    for (int m = 0; m < 8; ++m) {
      const int kvi = wm * 128 + m * 16 + l16;
      kf[m] = *(const bf16x8*)(Kp + (size_t)kvi * 768 + ks * 32 + lhi * 8);
    }
#pragma unroll
    for (int nf = 0; nf < 2; ++nf) {
      const int n = wn * 32 + nf * 16 + l16;
      qf[nf] = *(const bf16x8*)(Qp + (size_t)n * 2304 + ks * 32 + lhi * 8);
    }
#pragma unroll
    for (int m = 0; m < 8; ++m)
#pragma unroll
      for (int nf = 0; nf < 2; ++nf)
        st[m][nf] = __builtin_amdgcn_mfma_f32_16x16x32_bf16(kf[m], qf[nf], st[m][nf], 0, 0, 0);
  }

  float pmax[2] = {-50.f, -50.f};
#pragma unroll
  for (int m = 0; m < 8; ++m)
#pragma unroll
    for (int nf = 0; nf < 2; ++nf)
#pragma unroll
      for (int r = 0; r < 4; ++r) {
        float v = fminf(fmaxf(st[m][nf][r] * 0.125f, -50.f), 50.f);
        st[m][nf][r] = v;
        pmax[nf] = fmaxf(pmax[nf], v);
      }
#pragma unroll
  for (int nf = 0; nf < 2; ++nf) {
    pmax[nf] = fmaxf(pmax[nf], __shfl_xor(pmax[nf], 16));
    pmax[nf] = fmaxf(pmax[nf], __shfl_xor(pmax[nf], 32));
  }
  if (lhi == 0) {
#pragma unroll
    for (int nf = 0; nf < 2; ++nf) redm[wm][wn * 32 + nf * 16 + l16] = pmax[nf];
  }
  __syncthreads();
  float M[2];
#pragma unroll
  for (int nf = 0; nf < 2; ++nf) {
    const int col = wn * 32 + nf * 16 + l16;
    M[nf] = fmaxf(redm[0][col], redm[1][col]);
  }

  float psum[2] = {0.f, 0.f};
#pragma unroll
  for (int m = 0; m < 8; ++m) {
#pragma unroll
    for (int nf = 0; nf < 2; ++nf) {
      float e0 = __expf(st[m][nf][0] - M[nf]);
      float e1 = __expf(st[m][nf][1] - M[nf]);
      float e2 = __expf(st[m][nf][2] - M[nf]);
      float e3 = __expf(st[m][nf][3] - M[nf]);
      psum[nf] += (e0 + e1) + (e2 + e3);
      uint2 pk;
      pk.x = (uint32_t)f2bf(e0) | ((uint32_t)f2bf(e1) << 16);
      pk.y = (uint32_t)f2bf(e2) | ((uint32_t)f2bf(e3) << 16);
      const int n = wn * 32 + nf * 16 + l16;
      const int kvb2 = (wm * 128 + m * 16 + lhi * 4) * 2;
      *(uint2*)((char*)sP + n * 512 + (kvb2 ^ ((n & 7) << 4))) = pk;
    }
  }
#pragma unroll
  for (int nf = 0; nf < 2; ++nf) {
    psum[nf] += __shfl_xor(psum[nf], 16);
    psum[nf] += __shfl_xor(psum[nf], 32);
  }
  if (lhi == 0) {
#pragma unroll
    for (int nf = 0; nf < 2; ++nf) reds[wm][wn * 32 + nf * 16 + l16] = psum[nf];
  }
  __syncthreads();
  if (wm == 0 && lhi == 0) {
#pragma unroll
    for (int nf = 0; nf < 2; ++nf) {
      const int col = wn * 32 + nf * 16 + l16;
      recs[col] = 1.f / (reds[0][col] + reds[1][col]);
    }
  }
  __syncthreads();

  f32x4 pacc[2][2];
#pragma unroll
  for (int mf = 0; mf < 2; ++mf)
#pragma unroll
    for (int nf = 0; nf < 2; ++nf) pacc[mf][nf] = f32x4{0.f, 0.f, 0.f, 0.f};
#pragma unroll
  for (int ks = 0; ks < 8; ++ks) {
    bf16x8 pa[2], vb[2];
#pragma unroll
    for (int mf = 0; mf < 2; ++mf) {
      const int n = wm * 32 + mf * 16 + l16;
      pa[mf] = *(const bf16x8*)((char*)sP + n * 512 + ((ks * 64 + lhi * 16) ^ ((n & 7) << 4)));
    }
#pragma unroll
    for (int nf = 0; nf < 2; ++nf) {
      const int d = wn * 32 + nf * 16 + l16;
      vb[nf] = *(const bf16x8*)(Vp + (size_t)d * 256 + ks * 32 + lhi * 8);
    }
#pragma unroll
    for (int mf = 0; mf < 2; ++mf)
#pragma unroll
      for (int nf = 0; nf < 2; ++nf)
        pacc[mf][nf] = __builtin_amdgcn_mfma_f32_16x16x32_bf16(pa[mf], vb[nf], pacc[mf][nf], 0, 0, 0);
  }
  uint16_t* orow = o + ((size_t)b * 8192 + n0) * 768 + h * 64;
#pragma unroll
  for (int mf = 0; mf < 2; ++mf) {
#pragma unroll
    for (int r = 0; r < 4; ++r) {
      const int n = wm * 32 + mf * 16 + lhi * 4 + r;
      const float inv = recs[n];
#pragma unroll
      for (int nf = 0; nf < 2; ++nf) {
        const int d = wn * 32 + nf * 16 + l16;
        orow[(size_t)n * 768 + d] = f2bf(pacc[mf][nf][r] * inv);
      }
    }
  }
}

// ======== gemm128: 128x128 NT GEMM, BK=32, 3 LDS buffers (48 KB), 3 blocks/CU,
// 4 waves (2x2), counted vmcnt(4) once per K-tile (never 0 in main loop),
// ONE barrier per K-tile, XOR swizzle, setprio, bijective XCD swizzle.
// C[M,N] = A[M,K] @ B[N,K]^T.
template <bool OUTBF, bool HASBIAS, bool DOGELU, bool HASRES>
__global__ __launch_bounds__(256, 3) void gemm128(
    const uint16_t* __restrict__ A, const uint16_t* __restrict__ B,
    void* __restrict__ Cbase, const float* __restrict__ bias,
    const float* __restrict__ res, int Kd, int lda, int ldb, int ldc) {
  constexpr int PL = 4096;  // one operand plane: 128 rows x 32 cols (8 KB)
  __shared__ __align__(16) uint16_t lds[3 * 2 * PL];  // 48 KB

  const int nn = gridDim.y;
  const int nwg = gridDim.x * gridDim.y;
  const int bid = blockIdx.y * gridDim.x + blockIdx.x;
  const int q = nwg >> 3, r8 = nwg & 7, xcd = bid & 7, idx = bid >> 3;
  const int wg = (xcd < r8 ? xcd * (q + 1) : r8 * (q + 1) + (xcd - r8) * q) + idx;
  const int bm = wg / nn, bn = wg % nn;
  const int row0 = bm * 128, col0 = bn * 128;

  const int tid = threadIdx.x;
  const int wave = tid >> 6, lane = tid & 63;
  const int wm = wave >> 1, wn = wave & 1;
  const int l16 = lane & 15, lhi = lane >> 4;
  const int srow = tid >> 2, sq = tid & 3;

  // stage K-tile t into buffer buf: 4 x gload16 (A 2, B 2), 64 rows per inst
  auto stage = [&](int buf, int t) {
    const int k0 = t * 32;
    uint16_t* sa = lds + buf * 2 * PL;
#pragma unroll
    for (int j = 0; j < 2; ++j) {
      const int rw = j * 64 + srow;
      const int sl = sq ^ ((rw >> 1) & 3);  // pre-swizzled global slot
      gload16(A + (size_t)(row0 + rw) * lda + k0 + sl * 8, sa + rw * 32 + sq * 8);
    }
#pragma unroll
    for (int j = 0; j < 2; ++j) {
      const int rw = j * 64 + srow;
      const int sl = sq ^ ((rw >> 1) & 3);
      gload16(B + (size_t)(col0 + rw) * ldb + k0 + sl * 8, sa + PL + rw * 32 + sq * 8);
    }
  };

  f32x4 acc[4][4];
#pragma unroll
  for (int m = 0; m < 4; ++m)
#pragma unroll
    for (int n = 0; n < 4; ++n) acc[m][n] = f32x4{0.f, 0.f, 0.f, 0.f};

  const int NT = Kd >> 5;  // >= 24 for all our shapes
  stage(0, 0);
  stage(1, 1);

  for (int t = 0; t < NT; ++t) {
    if (t < NT - 1) waitcnt_vm<4>();  // certify tile t; tile t+1 stays in flight
    else waitcnt_vm<0>();
    __builtin_amdgcn_s_barrier();
    asm volatile("" ::: "memory");
    if (t + 2 < NT) stage((t + 2) % 3, t + 2);

    const uint16_t* sa = lds + (t % 3) * 2 * PL;
    const uint16_t* sb = sa + PL;
    bf16x8 af[4], bfv[4];
#pragma unroll
    for (int n = 0; n < 4; ++n) {
      const int rw = wn * 64 + n * 16 + l16;
      bfv[n] = *(const bf16x8*)(sb + rw * 32 + (lhi ^ ((rw >> 1) & 3)) * 8);
    }
#pragma unroll
    for (int m = 0; m < 4; ++m) {
      const int rw = wm * 64 + m * 16 + l16;
      af[m] = *(const bf16x8*)(sa + rw * 32 + (lhi ^ ((rw >> 1) & 3)) * 8);
    }
    __builtin_amdgcn_s_setprio(1);
#pragma unroll
    for (int m = 0; m < 4; ++m)
#pragma unroll
      for (int n = 0; n < 4; ++n)
        acc[m][n] = __builtin_amdgcn_mfma_f32_16x16x32_bf16(af[m], bfv[n], acc[m][n], 0, 0, 0);
    __builtin_amdgcn_s_setprio(0);
  }

  float* Cf = (float*)Cbase;
  uint16_t* Cb = (uint16_t*)Cbase;
#pragma unroll
  for (int m = 0; m < 4; ++m) {
#pragma unroll
    for (int n = 0; n < 4; ++n) {
      const int col = col0 + wn * 64 + n * 16 + l16;
      float bv = 0.f;
      if (HASBIAS) bv = bias[col];
#pragma unroll
      for (int r = 0; r < 4; ++r) {
        const int row = row0 + wm * 64 + m * 16 + lhi * 4 + r;
        float v = acc[m][n][r] + bv;
        if (DOGELU) v = gelu_f(v);
        const size_t cidx = (size_t)row * ldc + col;
        if (HASRES) v += res[cidx];
        if (OUTBF) Cb[cidx] = f2bf(v);
        else Cf[cidx] = v;
      }
    }
  }
}

extern "C" void kernel_launch(void* const* d_in, const int* in_sizes, int n_in,
                              void* d_out, int out_size, void* d_ws, size_t ws_size,
                              hipStream_t stream) {
  const float* x      = (const float*)d_in[0];
  const float* ln1_w  = (const float*)d_in[1];
  const float* ln1_b  = (const float*)d_in[2];
  const float* qkv_w  = (const float*)d_in[3];
  const float* qkv_b  = (const float*)d_in[4];
  const float* Ek     = (const float*)d_in[5];
  const float* Ev     = (const float*)d_in[6];
  const float* proj_w = (const float*)d_in[7];
  const float* proj_b = (const float*)d_in[8];
  const float* ln2_w  = (const float*)d_in[9];
  const float* ln2_b  = (const float*)d_in[10];
  const float* fc1_w  = (const float*)d_in[11];
  const float* fc1_b  = (const float*)d_in[12];
  const float* fc2_w  = (const float*)d_in[13];
  const float* fc2_b  = (const float*)d_in[14];
  float* out = (float*)d_out;

  char* w8 = (char*)d_ws;
  size_t off = 0;
  auto take = [&](size_t bytes) { char* p = w8 + off; off += bytes; return p; };
  uint16_t* qkv_wT  = (uint16_t*)take(2304ull * 768 * 2);
  uint16_t* proj_wT = (uint16_t*)take(768ull * 768 * 2);
  uint16_t* fc1_wT  = (uint16_t*)take(3072ull * 768 * 2);
  uint16_t* fc2_wT  = (uint16_t*)take(768ull * 3072 * 2);
  uint16_t* EkT     = (uint16_t*)take(256ull * 8192 * 2);
  uint16_t* EvT     = (uint16_t*)take(256ull * 8192 * 2);
  uint16_t* h_bf    = (uint16_t*)take(16384ull * 768 * 2);
  uint16_t* qkv_bf  = (uint16_t*)take(16384ull * 2304 * 2);
  uint16_t* big     = (uint16_t*)take(100663296ull);
  uint16_t* kproj   = (uint16_t*)take(2ull * 2 * 256 * 768 * 2);
  uint16_t* vprojT  = (uint16_t*)take(2ull * 768 * 256 * 2);
  uint16_t* o_bf    = (uint16_t*)take(16384ull * 768 * 2);
  float* part = (float*)big;  // 16 * 196608 * 4B, used before fc1
  (void)ws_size; (void)in_sizes; (void)n_in; (void)out_size;

  const dim3 tb(32, 8);
  // 1) weights / projections -> bf16 transposed (all GEMMs NT)
  transpose_f2b<<<dim3(72, 24), tb, 0, stream>>>(qkv_w, qkv_wT, 2304, 768);
  transpose_f2b<<<dim3(24, 24), tb, 0, stream>>>(proj_w, proj_wT, 768, 768);
  transpose_f2b<<<dim3(96, 24), tb, 0, stream>>>(fc1_w, fc1_wT, 3072, 768);
  transpose_f2b<<<dim3(24, 96), tb, 0, stream>>>(fc2_w, fc2_wT, 768, 3072);
  transpose_f2b<<<dim3(8, 256), tb, 0, stream>>>(Ek, EkT, 256, 8192);
  transpose_f2b<<<dim3(8, 256), tb, 0, stream>>>(Ev, EvT, 256, 8192);
  // 2) LN1
  ln768<<<16384, 256, 0, stream>>>(x, ln1_w, ln1_b, h_bf);
  // 3) qkv = h @ qkv_w + b    grid 2304 = 3 x 768
  gemm128<true, true, false, false><<<dim3(128, 18), 256, 0, stream>>>(
      h_bf, qkv_wT, qkv_bf, qkv_b, nullptr, 768, 768, 768, 2304);
  // 4) kv_proj: TN gather GEMM, n-split 4 -> fp32 partials, then reduce
  kv_tn<<<768, 256, 0, stream>>>(EkT, EvT, qkv_bf, part);
  kv_reduce<<<dim3(768, 4), 256, 0, stream>>>(part, kproj);
  // 5) v_projT[b] [768,256]
  for (int b = 0; b < 2; ++b)
    transpose_b2b<<<dim3(24, 8), tb, 0, stream>>>(
        kproj + (size_t)(2 + b) * 196608, vprojT + (size_t)b * 768 * 256, 768, 256);
  // 6) fused attention -> o_bf
  attn_fused<<<dim3(128, 24), 256, 0, stream>>>(qkv_bf, kproj, vprojT, o_bf);
  // 7) x2 = x + o @ proj_w + b -> d_out (fp32)   grid 768
  gemm128<false, true, false, true><<<dim3(128, 6), 256, 0, stream>>>(
      o_bf, proj_wT, out, proj_b, x, 768, 768, 768, 768);
  // 8) LN2
  ln768<<<16384, 256, 0, stream>>>(out, ln2_w, ln2_b, h_bf);
  // 9) a1 = gelu(h2 @ fc1_w + b) -> big   grid 3072 = 4 x 768
  gemm128<true, true, true, false><<<dim3(128, 24), 256, 0, stream>>>(
      h_bf, fc1_wT, big, fc1_b, nullptr, 768, 768, 768, 3072);
  // 10) out = x2 + a1 @ fc2_w + b (in-place residual)   grid 768
  gemm128<false, true, false, true><<<dim3(128, 6), 256, 0, stream>>>(
      big, fc2_wT, out, fc2_b, out, 3072, 3072, 3072, 768);
}

// Round 7
// 473.296 us; speedup vs baseline: 1.1082x; 1.0859x over previous
//
#include <hip/hip_runtime.h>
#include <cstdint>

#define DEV __device__ __forceinline__

typedef __bf16 bf16x8 __attribute__((ext_vector_type(8)));
typedef float f32x4 __attribute__((ext_vector_type(4)));

DEV uint16_t f2bf(float f) {
  uint32_t u = __float_as_uint(f);
  u += 0x7FFFu + ((u >> 16) & 1u);
  return (uint16_t)(u >> 16);
}
DEV float bf2f(uint16_t h) { return __uint_as_float(((uint32_t)h) << 16); }

DEV void gload16(const void* g, void* l) {
  __builtin_amdgcn_global_load_lds((const __attribute__((address_space(1))) void*)g,
                                   (__attribute__((address_space(3))) void*)l, 16, 0, 0);
}

template <int N> DEV void waitcnt_vm() {
  if constexpr (N == 0) asm volatile("s_waitcnt vmcnt(0)" ::: "memory");
  else if constexpr (N == 4) asm volatile("s_waitcnt vmcnt(4)" ::: "memory");
  else if constexpr (N == 6) asm volatile("s_waitcnt vmcnt(6)" ::: "memory");
  else static_assert(N == 0 || N == 4 || N == 6, "unsupported vmcnt");
}

// fast GELU (tanh form): max abs err vs erf-GELU ~3e-3
DEV float gelu_f(float v) {
  float u = v * (0.7978845608f + 0.0356774081f * v * v);
  return v / (1.f + __expf(-2.f * u));
}

// ---------------- LayerNorm over C=768, fp32 in -> bf16 out ----------------
__global__ __launch_bounds__(256) void ln768(const float* __restrict__ x,
                                             const float* __restrict__ w,
                                             const float* __restrict__ b,
                                             uint16_t* __restrict__ out) {
  const size_t row = blockIdx.x;
  const float* xr = x + row * 768;
  const int t = threadIdx.x;
  float v0 = xr[t], v1 = xr[t + 256], v2 = xr[t + 512];
  float s = v0 + v1 + v2;
  float s2 = v0 * v0 + v1 * v1 + v2 * v2;
#pragma unroll
  for (int o = 32; o; o >>= 1) {
    s += __shfl_down(s, o);
    s2 += __shfl_down(s2, o);
  }
  __shared__ float sh[8];
  if ((t & 63) == 0) { sh[t >> 6] = s; sh[4 + (t >> 6)] = s2; }
  __syncthreads();
  s = sh[0] + sh[1] + sh[2] + sh[3];
  s2 = sh[4] + sh[5] + sh[6] + sh[7];
  const float mu = s * (1.f / 768.f);
  const float var = s2 * (1.f / 768.f) - mu * mu;
  const float rstd = rsqrtf(var + 1e-6f);
  uint16_t* orow = out + row * 768;
  orow[t]       = f2bf((v0 - mu) * rstd * w[t] + b[t]);
  orow[t + 256] = f2bf((v1 - mu) * rstd * w[t + 256] + b[t + 256]);
  orow[t + 512] = f2bf((v2 - mu) * rstd * w[t + 512] + b[t + 512]);
}

// ---------------- transpose fp32 [R,Cc] -> bf16 [Cc,R] ----------------
__global__ __launch_bounds__(256) void transpose_f2b(const float* __restrict__ in,
                                                     uint16_t* __restrict__ outp,
                                                     int ldin, int ldout) {
  __shared__ float tile[32][33];
  const int tx = threadIdx.x, ty = threadIdx.y;
  const size_t x = (size_t)blockIdx.x * 32 + tx;
  const size_t y = (size_t)blockIdx.y * 32 + ty;
#pragma unroll
  for (int j = 0; j < 4; ++j) tile[ty + j * 8][tx] = in[(y + j * 8) * ldin + x];
  __syncthreads();
  const size_t x2 = (size_t)blockIdx.y * 32 + tx;
  const size_t y2 = (size_t)blockIdx.x * 32 + ty;
#pragma unroll
  for (int j = 0; j < 4; ++j) outp[(y2 + j * 8) * ldout + x2] = f2bf(tile[tx][ty + j * 8]);
}

// ---------------- transpose bf16 [R,Cc] -> bf16 [Cc,R] ----------------
__global__ __launch_bounds__(256) void transpose_b2b(const uint16_t* __restrict__ in,
                                                     uint16_t* __restrict__ outp,
                                                     int ldin, int ldout) {
  __shared__ uint16_t tile[32][33];
  const int tx = threadIdx.x, ty = threadIdx.y;
  const size_t x = (size_t)blockIdx.x * 32 + tx;
  const size_t y = (size_t)blockIdx.y * 32 + ty;
#pragma unroll
  for (int j = 0; j < 4; ++j) tile[ty + j * 8][tx] = in[(y + j * 8) * ldin + x];
  __syncthreads();
  const size_t x2 = (size_t)blockIdx.y * 32 + tx;
  const size_t y2 = (size_t)blockIdx.x * 32 + ty;
#pragma unroll
  for (int j = 0; j < 4; ++j) outp[(y2 + j * 8) * ldout + x2] = tile[tx][ty + j * 8];
}

// -------- rowsum of EKV_T [512][8192] bf16 -> colsum[512] fp32 (one wave/row)
__global__ __launch_bounds__(256) void rowsum512(const uint16_t* __restrict__ ekv,
                                                 float* __restrict__ colsum) {
  const int row = blockIdx.x * 4 + (threadIdx.x >> 6);
  const int lane = threadIdx.x & 63;
  const uint16_t* r = ekv + (size_t)row * 8192 + lane * 8;
  float s = 0.f;
#pragma unroll
  for (int it = 0; it < 16; ++it) {
    bf16x8 v = *(const bf16x8*)(r + it * 512);
#pragma unroll
    for (int j = 0; j < 8; ++j) s += (float)v[j];
  }
#pragma unroll
  for (int o = 32; o; o >>= 1) s += __shfl_down(s, o);
  if (lane == 0) colsum[row] = s;
}

// -------- reduce 4 split-K fp32 partials [4][2*512*768] -> bf16 hkv
__global__ __launch_bounds__(256) void kv_reduce(const float* __restrict__ part,
                                                 uint16_t* __restrict__ hkv) {
  const int i = blockIdx.x * 256 + threadIdx.x;  // [0, 786432)
  float s = part[i] + part[786432 + i] + part[2 * 786432 + i] + part[3 * 786432 + i];
  hkv[i] = f2bf(s);
}

// ---------------- generic small NT GEMM with z-batching (kv path) ----------
// C = A @ B^T (+ rowscale[row]*bias[col] if HASRS else + bias[col])
template <int BM, int BN, bool OUTBF, bool HASBIAS, bool DOGELU, bool HASRES, bool HASRS>
__global__ __launch_bounds__(256) void gemm_nt(
    const uint16_t* __restrict__ Abase, const uint16_t* __restrict__ Bbase,
    void* __restrict__ Cbase, const float* __restrict__ bias,
    const float* __restrict__ resbase, const float* __restrict__ rowscale,
    int Kd, int lda, int ldb, int ldc,
    int zdiv, size_t sAhi, size_t sAlo, size_t sBhi, size_t sBlo,
    size_t sChi, size_t sClo, int rs_z, int bias_z) {
  const int z = blockIdx.z;
  const int zhi = z / zdiv, zlo = z - zhi * zdiv;
  const uint16_t* A = Abase + zhi * sAhi + zlo * sAlo;
  const uint16_t* B = Bbase + zhi * sBhi + zlo * sBlo;
  const size_t coff = zhi * sChi + zlo * sClo;

  constexpr int WTM = BM / 2, WTN = BN / 2;
  constexpr int FM = WTM / 16, FN = WTN / 16;
  const int tid = threadIdx.x;
  const int wave = tid >> 6, lane = tid & 63;
  const int wm = wave >> 1, wn = wave & 1;
  const int l16 = lane & 15, lhi = lane >> 4;

  __shared__ __align__(16) uint16_t sA[BM * 32];
  __shared__ __align__(16) uint16_t sB[BN * 32];

  f32x4 acc[FM][FN];
#pragma unroll
  for (int m = 0; m < FM; ++m)
#pragma unroll
    for (int n = 0; n < FN; ++n) acc[m][n] = f32x4{0.f, 0.f, 0.f, 0.f};

  const int row0 = blockIdx.x * BM;
  const int col0 = blockIdx.y * BN;
  const int rr = tid >> 2, cq = tid & 3;

  for (int k0 = 0; k0 < Kd; k0 += 32) {
    __syncthreads();
#pragma unroll
    for (int is = 0; is < BM / 64; ++is) {
      const uint16_t* g = A + (size_t)(row0 + is * 64 + rr) * lda + k0 + cq * 8;
      gload16(g, &sA[is * 2048 + tid * 8]);
    }
#pragma unroll
    for (int is = 0; is < BN / 64; ++is) {
      const uint16_t* g = B + (size_t)(col0 + is * 64 + rr) * ldb + k0 + cq * 8;
      gload16(g, &sB[is * 2048 + tid * 8]);
    }
    __syncthreads();

    bf16x8 af[FM], bq[FN];
#pragma unroll
    for (int m = 0; m < FM; ++m)
      af[m] = *(const bf16x8*)(&sA[(wm * WTM + m * 16 + l16) * 32 + lhi * 8]);
#pragma unroll
    for (int n = 0; n < FN; ++n)
      bq[n] = *(const bf16x8*)(&sB[(wn * WTN + n * 16 + l16) * 32 + lhi * 8]);
#pragma unroll
    for (int m = 0; m < FM; ++m)
#pragma unroll
      for (int n = 0; n < FN; ++n)
        acc[m][n] = __builtin_amdgcn_mfma_f32_16x16x32_bf16(af[m], bq[n], acc[m][n], 0, 0, 0);
  }

  float* Cf = (float*)Cbase;
  uint16_t* Cb = (uint16_t*)Cbase;
#pragma unroll
  for (int m = 0; m < FM; ++m) {
#pragma unroll
    for (int n = 0; n < FN; ++n) {
      const int col = col0 + wn * WTN + n * 16 + l16;
      float bv = 0.f;
      if (HASBIAS) bv = bias[zlo * bias_z + col];
#pragma unroll
      for (int r = 0; r < 4; ++r) {
        const int row = row0 + wm * WTM + m * 16 + lhi * 4 + r;
        float v = acc[m][n][r];
        if (HASBIAS) {
          if (HASRS) v += rowscale[zlo * rs_z + row] * bv;
          else v += bv;
        }
        if (DOGELU) v = gelu_f(v);
        const size_t cidx = coff + (size_t)row * ldc + col;
        if (HASRES) v += resbase[cidx];
        if (OUTBF) Cb[cidx] = f2bf(v);
        else Cf[cidx] = v;
      }
    }
  }
}

// ======== fused attention: one (qtile64, b, h) block ========
__global__ __launch_bounds__(256, 3) void attn_fused(
    const uint16_t* __restrict__ q,      // [2][8192][768]
    const uint16_t* __restrict__ kproj,  // [4][256][768]
    const uint16_t* __restrict__ vprojT, // [2][768][256]
    uint16_t* __restrict__ o) {          // [2][8192][768]
  const int bh = blockIdx.y;
  const int b = bh / 12, h = bh % 12;
  const int n0 = blockIdx.x * 64;
  const int tid = threadIdx.x, wave = tid >> 6, lane = tid & 63;
  const int l16 = lane & 15, lhi = lane >> 4;
  const int wm = wave >> 1, wn = wave & 1;

  __shared__ __align__(16) uint16_t sP[64 * 256];
  __shared__ float redm[2][64], reds[2][64], recs[64];

  const uint16_t* Kp = kproj + (size_t)b * 196608 + h * 64;
  const uint16_t* Qp = q + ((size_t)b * 8192 + n0) * 768 + h * 64;
  const uint16_t* Vp = vprojT + ((size_t)b * 768 + h * 64) * 256;

  f32x4 st[8][2];
#pragma unroll
  for (int m = 0; m < 8; ++m)
#pragma unroll
    for (int nf = 0; nf < 2; ++nf) st[m][nf] = f32x4{0.f, 0.f, 0.f, 0.f};
#pragma unroll
  for (int ks = 0; ks < 2; ++ks) {
    bf16x8 kf[8], qf[2];
#pragma unroll
    for (int m = 0; m < 8; ++m) {
      const int kvi = wm * 128 + m * 16 + l16;
      kf[m] = *(const bf16x8*)(Kp + (size_t)kvi * 768 + ks * 32 + lhi * 8);
    }
#pragma unroll
    for (int nf = 0; nf < 2; ++nf) {
      const int n = wn * 32 + nf * 16 + l16;
      qf[nf] = *(const bf16x8*)(Qp + (size_t)n * 768 + ks * 32 + lhi * 8);
    }
#pragma unroll
    for (int m = 0; m < 8; ++m)
#pragma unroll
      for (int nf = 0; nf < 2; ++nf)
        st[m][nf] = __builtin_amdgcn_mfma_f32_16x16x32_bf16(kf[m], qf[nf], st[m][nf], 0, 0, 0);
  }

  float pmax[2] = {-50.f, -50.f};
#pragma unroll
  for (int m = 0; m < 8; ++m)
#pragma unroll
    for (int nf = 0; nf < 2; ++nf)
#pragma unroll
      for (int r = 0; r < 4; ++r) {
        float v = fminf(fmaxf(st[m][nf][r] * 0.125f, -50.f), 50.f);
        st[m][nf][r] = v;
        pmax[nf] = fmaxf(pmax[nf], v);
      }
#pragma unroll
  for (int nf = 0; nf < 2; ++nf) {
    pmax[nf] = fmaxf(pmax[nf], __shfl_xor(pmax[nf], 16));
    pmax[nf] = fmaxf(pmax[nf], __shfl_xor(pmax[nf], 32));
  }
  if (lhi == 0) {
#pragma unroll
    for (int nf = 0; nf < 2; ++nf) redm[wm][wn * 32 + nf * 16 + l16] = pmax[nf];
  }
  __syncthreads();
  float M[2];
#pragma unroll
  for (int nf = 0; nf < 2; ++nf) {
    const int col = wn * 32 + nf * 16 + l16;
    M[nf] = fmaxf(redm[0][col], redm[1][col]);
  }

  float psum[2] = {0.f, 0.f};
#pragma unroll
  for (int m = 0; m < 8; ++m) {
#pragma unroll
    for (int nf = 0; nf < 2; ++nf) {
      float e0 = __expf(st[m][nf][0] - M[nf]);
      float e1 = __expf(st[m][nf][1] - M[nf]);
      float e2 = __expf(st[m][nf][2] - M[nf]);
      float e3 = __expf(st[m][nf][3] - M[nf]);
      psum[nf] += (e0 + e1) + (e2 + e3);
      uint2 pk;
      pk.x = (uint32_t)f2bf(e0) | ((uint32_t)f2bf(e1) << 16);
      pk.y = (uint32_t)f2bf(e2) | ((uint32_t)f2bf(e3) << 16);
      const int n = wn * 32 + nf * 16 + l16;
      const int kvb2 = (wm * 128 + m * 16 + lhi * 4) * 2;
      *(uint2*)((char*)sP + n * 512 + (kvb2 ^ ((n & 7) << 4))) = pk;
    }
  }
#pragma unroll
  for (int nf = 0; nf < 2; ++nf) {
    psum[nf] += __shfl_xor(psum[nf], 16);
    psum[nf] += __shfl_xor(psum[nf], 32);
  }
  if (lhi == 0) {
#pragma unroll
    for (int nf = 0; nf < 2; ++nf) reds[wm][wn * 32 + nf * 16 + l16] = psum[nf];
  }
  __syncthreads();
  if (wm == 0 && lhi == 0) {
#pragma unroll
    for (int nf = 0; nf < 2; ++nf) {
      const int col = wn * 32 + nf * 16 + l16;
      recs[col] = 1.f / (reds[0][col] + reds[1][col]);
    }
  }
  __syncthreads();

  f32x4 pacc[2][2];
#pragma unroll
  for (int mf = 0; mf < 2; ++mf)
#pragma unroll
    for (int nf = 0; nf < 2; ++nf) pacc[mf][nf] = f32x4{0.f, 0.f, 0.f, 0.f};
#pragma unroll
  for (int ks = 0; ks < 8; ++ks) {
    bf16x8 pa[2], vb[2];
#pragma unroll
    for (int mf = 0; mf < 2; ++mf) {
      const int n = wm * 32 + mf * 16 + l16;
      pa[mf] = *(const bf16x8*)((char*)sP + n * 512 + ((ks * 64 + lhi * 16) ^ ((n & 7) << 4)));
    }
#pragma unroll
    for (int nf = 0; nf < 2; ++nf) {
      const int d = wn * 32 + nf * 16 + l16;
      vb[nf] = *(const bf16x8*)(Vp + (size_t)d * 256 + ks * 32 + lhi * 8);
    }
#pragma unroll
    for (int mf = 0; mf < 2; ++mf)
#pragma unroll
      for (int nf = 0; nf < 2; ++nf)
        pacc[mf][nf] = __builtin_amdgcn_mfma_f32_16x16x32_bf16(pa[mf], vb[nf], pacc[mf][nf], 0, 0, 0);
  }
  uint16_t* orow = o + ((size_t)b * 8192 + n0) * 768 + h * 64;
#pragma unroll
  for (int mf = 0; mf < 2; ++mf) {
#pragma unroll
    for (int r = 0; r < 4; ++r) {
      const int n = wm * 32 + mf * 16 + lhi * 4 + r;
      const float inv = recs[n];
#pragma unroll
      for (int nf = 0; nf < 2; ++nf) {
        const int d = wn * 32 + nf * 16 + l16;
        orow[(size_t)n * 768 + d] = f2bf(pacc[mf][nf][r] * inv);
      }
    }
  }
}

// ======== gemm128: 128x128 NT, BK=32, 3 bufs (48 KB), 3 blocks/CU ========
template <bool OUTBF, bool HASBIAS, bool DOGELU, bool HASRES>
__global__ __launch_bounds__(256, 3) void gemm128(
    const uint16_t* __restrict__ A, const uint16_t* __restrict__ B,
    void* __restrict__ Cbase, const float* __restrict__ bias,
    const float* __restrict__ res, int Kd, int lda, int ldb, int ldc) {
  constexpr int PL = 4096;
  __shared__ __align__(16) uint16_t lds[3 * 2 * PL];

  const int nn = gridDim.y;
  const int nwg = gridDim.x * gridDim.y;
  const int bid = blockIdx.y * gridDim.x + blockIdx.x;
  const int q = nwg >> 3, r8 = nwg & 7, xcd = bid & 7, idx = bid >> 3;
  const int wg = (xcd < r8 ? xcd * (q + 1) : r8 * (q + 1) + (xcd - r8) * q) + idx;
  const int bm = wg / nn, bn = wg % nn;
  const int row0 = bm * 128, col0 = bn * 128;

  const int tid = threadIdx.x;
  const int wave = tid >> 6, lane = tid & 63;
  const int wm = wave >> 1, wn = wave & 1;
  const int l16 = lane & 15, lhi = lane >> 4;
  const int srow = tid >> 2, sq = tid & 3;

  auto stage = [&](int buf, int t) {
    const int k0 = t * 32;
    uint16_t* sa = lds + buf * 2 * PL;
#pragma unroll
    for (int j = 0; j < 2; ++j) {
      const int rw = j * 64 + srow;
      const int sl = sq ^ ((rw >> 1) & 3);
      gload16(A + (size_t)(row0 + rw) * lda + k0 + sl * 8, sa + rw * 32 + sq * 8);
    }
#pragma unroll
    for (int j = 0; j < 2; ++j) {
      const int rw = j * 64 + srow;
      const int sl = sq ^ ((rw >> 1) & 3);
      gload16(B + (size_t)(col0 + rw) * ldb + k0 + sl * 8, sa + PL + rw * 32 + sq * 8);
    }
  };

  f32x4 acc[4][4];
#pragma unroll
  for (int m = 0; m < 4; ++m)
#pragma unroll
    for (int n = 0; n < 4; ++n) acc[m][n] = f32x4{0.f, 0.f, 0.f, 0.f};

  const int NT = Kd >> 5;
  stage(0, 0);
  stage(1, 1);

  for (int t = 0; t < NT; ++t) {
    if (t < NT - 1) waitcnt_vm<4>();
    else waitcnt_vm<0>();
    __builtin_amdgcn_s_barrier();
    asm volatile("" ::: "memory");
    if (t + 2 < NT) stage((t + 2) % 3, t + 2);

    const uint16_t* sa = lds + (t % 3) * 2 * PL;
    const uint16_t* sb = sa + PL;
    bf16x8 af[4], bfv[4];
#pragma unroll
    for (int n = 0; n < 4; ++n) {
      const int rw = wn * 64 + n * 16 + l16;
      bfv[n] = *(const bf16x8*)(sb + rw * 32 + (lhi ^ ((rw >> 1) & 3)) * 8);
    }
#pragma unroll
    for (int m = 0; m < 4; ++m) {
      const int rw = wm * 64 + m * 16 + l16;
      af[m] = *(const bf16x8*)(sa + rw * 32 + (lhi ^ ((rw >> 1) & 3)) * 8);
    }
    __builtin_amdgcn_s_setprio(1);
#pragma unroll
    for (int m = 0; m < 4; ++m)
#pragma unroll
      for (int n = 0; n < 4; ++n)
        acc[m][n] = __builtin_amdgcn_mfma_f32_16x16x32_bf16(af[m], bfv[n], acc[m][n], 0, 0, 0);
    __builtin_amdgcn_s_setprio(0);
  }

  float* Cf = (float*)Cbase;
  uint16_t* Cb = (uint16_t*)Cbase;
#pragma unroll
  for (int m = 0; m < 4; ++m) {
#pragma unroll
    for (int n = 0; n < 4; ++n) {
      const int col = col0 + wn * 64 + n * 16 + l16;
      float bv = 0.f;
      if (HASBIAS) bv = bias[col];
#pragma unroll
      for (int r = 0; r < 4; ++r) {
        const int row = row0 + wm * 64 + m * 16 + lhi * 4 + r;
        float v = acc[m][n][r] + bv;
        if (DOGELU) v = gelu_f(v);
        const size_t cidx = (size_t)row * ldc + col;
        if (HASRES) v += res[cidx];
        if (OUTBF) Cb[cidx] = f2bf(v);
        else Cf[cidx] = v;
      }
    }
  }
}

// ======== gemm256n: 256x128 NT, wave-tile 128x64 (FM=8), BK=32, 3 bufs (72KB),
// 2 blocks/CU, 32 MFMA per barrier, counted vmcnt(6). ========
template <bool OUTBF, bool HASBIAS, bool DOGELU, bool HASRES>
__global__ __launch_bounds__(256, 2) void gemm256n(
    const uint16_t* __restrict__ A, const uint16_t* __restrict__ B,
    void* __restrict__ Cbase, const float* __restrict__ bias,
    const float* __restrict__ res, int Kd, int lda, int ldb, int ldc) {
  constexpr int APL = 8192, BPL = 4096;  // elements per plane
  __shared__ __align__(16) uint16_t lds[3 * (APL + BPL)];  // 72 KB

  const int nn = gridDim.y;
  const int nwg = gridDim.x * gridDim.y;
  const int bid = blockIdx.y * gridDim.x + blockIdx.x;
  const int q = nwg >> 3, r8 = nwg & 7, xcd = bid & 7, idx = bid >> 3;
  const int wg = (xcd < r8 ? xcd * (q + 1) : r8 * (q + 1) + (xcd - r8) * q) + idx;
  const int bm = wg / nn, bn = wg % nn;
  const int row0 = bm * 256, col0 = bn * 128;

  const int tid = threadIdx.x;
  const int wave = tid >> 6, lane = tid & 63;
  const int wm = wave >> 1, wn = wave & 1;
  const int l16 = lane & 15, lhi = lane >> 4;
  const int srow = tid >> 2, sq = tid & 3;

  auto stage = [&](int buf, int t) {
    const int k0 = t * 32;
    uint16_t* sa = lds + buf * (APL + BPL);
#pragma unroll
    for (int j = 0; j < 4; ++j) {
      const int rw = j * 64 + srow;
      const int sl = sq ^ ((rw >> 1) & 3);
      gload16(A + (size_t)(row0 + rw) * lda + k0 + sl * 8, sa + rw * 32 + sq * 8);
    }
#pragma unroll
    for (int j = 0; j < 2; ++j) {
      const int rw = j * 64 + srow;
      const int sl = sq ^ ((rw >> 1) & 3);
      gload16(B + (size_t)(col0 + rw) * ldb + k0 + sl * 8, sa + APL + rw * 32 + sq * 8);
    }
  };

  f32x4 acc[8][4];
#pragma unroll
  for (int m = 0; m < 8; ++m)
#pragma unroll
    for (int n = 0; n < 4; ++n) acc[m][n] = f32x4{0.f, 0.f, 0.f, 0.f};

  const int NT = Kd >> 5;
  stage(0, 0);
  stage(1, 1);

  for (int t = 0; t < NT; ++t) {
    if (t < NT - 1) waitcnt_vm<6>();
    else waitcnt_vm<0>();
    __builtin_amdgcn_s_barrier();
    asm volatile("" ::: "memory");
    if (t + 2 < NT) stage((t + 2) % 3, t + 2);

    const uint16_t* sa = lds + (t % 3) * (APL + BPL);
    const uint16_t* sb = sa + APL;
    bf16x8 af[8], bfv[4];
#pragma unroll
    for (int n = 0; n < 4; ++n) {
      const int rw = wn * 64 + n * 16 + l16;
      bfv[n] = *(const bf16x8*)(sb + rw * 32 + (lhi ^ ((rw >> 1) & 3)) * 8);
    }
#pragma unroll
    for (int m = 0; m < 8; ++m) {
      const int rw = wm * 128 + m * 16 + l16;
      af[m] = *(const bf16x8*)(sa + rw * 32 + (lhi ^ ((rw >> 1) & 3)) * 8);
    }
    __builtin_amdgcn_s_setprio(1);
#pragma unroll
    for (int m = 0; m < 8; ++m)
#pragma unroll
      for (int n = 0; n < 4; ++n)
        acc[m][n] = __builtin_amdgcn_mfma_f32_16x16x32_bf16(af[m], bfv[n], acc[m][n], 0, 0, 0);
    __builtin_amdgcn_s_setprio(0);
  }

  float* Cf = (float*)Cbase;
  uint16_t* Cb = (uint16_t*)Cbase;
#pragma unroll
  for (int m = 0; m < 8; ++m) {
#pragma unroll
    for (int n = 0; n < 4; ++n) {
      const int col = col0 + wn * 64 + n * 16 + l16;
      float bv = 0.f;
      if (HASBIAS) bv = bias[col];
#pragma unroll
      for (int r = 0; r < 4; ++r) {
        const int row = row0 + wm * 128 + m * 16 + lhi * 4 + r;
        float v = acc[m][n][r] + bv;
        if (DOGELU) v = gelu_f(v);
        const size_t cidx = (size_t)row * ldc + col;
        if (HASRES) v += res[cidx];
        if (OUTBF) Cb[cidx] = f2bf(v);
        else Cf[cidx] = v;
      }
    }
  }
}

extern "C" void kernel_launch(void* const* d_in, const int* in_sizes, int n_in,
                              void* d_out, int out_size, void* d_ws, size_t ws_size,
                              hipStream_t stream) {
  const float* x      = (const float*)d_in[0];
  const float* ln1_w  = (const float*)d_in[1];
  const float* ln1_b  = (const float*)d_in[2];
  const float* qkv_w  = (const float*)d_in[3];
  const float* qkv_b  = (const float*)d_in[4];
  const float* Ek     = (const float*)d_in[5];
  const float* Ev     = (const float*)d_in[6];
  const float* proj_w = (const float*)d_in[7];
  const float* proj_b = (const float*)d_in[8];
  const float* ln2_w  = (const float*)d_in[9];
  const float* ln2_b  = (const float*)d_in[10];
  const float* fc1_w  = (const float*)d_in[11];
  const float* fc1_b  = (const float*)d_in[12];
  const float* fc2_w  = (const float*)d_in[13];
  const float* fc2_b  = (const float*)d_in[14];
  float* out = (float*)d_out;

  char* w8 = (char*)d_ws;
  size_t off = 0;
  auto take = [&](size_t bytes) { char* p = w8 + off; off += bytes; return p; };
  uint16_t* qkv_wT  = (uint16_t*)take(2304ull * 768 * 2);
  uint16_t* proj_wT = (uint16_t*)take(768ull * 768 * 2);
  uint16_t* fc1_wT  = (uint16_t*)take(3072ull * 768 * 2);
  uint16_t* fc2_wT  = (uint16_t*)take(768ull * 3072 * 2);
  uint16_t* EkT     = (uint16_t*)take(256ull * 8192 * 2);   // EKV_T rows 0-255
  uint16_t* EvT     = (uint16_t*)take(256ull * 8192 * 2);   // EKV_T rows 256-511 (contiguous)
  uint16_t* h_bf    = (uint16_t*)take(16384ull * 768 * 2);
  uint16_t* hT      = (uint16_t*)take(2ull * 768 * 8192 * 2);  // [b][768][8192]
  uint16_t* q_bf    = (uint16_t*)take(16384ull * 768 * 2);
  uint16_t* big     = (uint16_t*)take(100663296ull);           // EKV partials -> fc1 out
  uint16_t* hkv_bf  = (uint16_t*)take(2ull * 512 * 768 * 2);   // [b][512][768]
  uint16_t* kproj   = (uint16_t*)take(4ull * 256 * 768 * 2);   // [kvb][256][768]
  uint16_t* vprojT  = (uint16_t*)take(2ull * 768 * 256 * 2);
  uint16_t* o_bf    = (uint16_t*)take(16384ull * 768 * 2);
  float* colsum     = (float*)take(512 * 4);
  float* part = (float*)big;  // [4][2*512*768] fp32 = 12.6 MB
  (void)ws_size; (void)in_sizes; (void)n_in; (void)out_size;

  const dim3 tb(32, 8);
  // 1) weights / projections -> bf16 transposed
  transpose_f2b<<<dim3(72, 24), tb, 0, stream>>>(qkv_w, qkv_wT, 2304, 768);
  transpose_f2b<<<dim3(24, 24), tb, 0, stream>>>(proj_w, proj_wT, 768, 768);
  transpose_f2b<<<dim3(96, 24), tb, 0, stream>>>(fc1_w, fc1_wT, 3072, 768);
  transpose_f2b<<<dim3(24, 96), tb, 0, stream>>>(fc2_w, fc2_wT, 768, 3072);
  transpose_f2b<<<dim3(8, 256), tb, 0, stream>>>(Ek, EkT, 256, 8192);
  transpose_f2b<<<dim3(8, 256), tb, 0, stream>>>(Ev, EvT, 256, 8192);
  // 2) LN1 -> h_bf; transpose h -> hT; colsum of E
  ln768<<<16384, 256, 0, stream>>>(x, ln1_w, ln1_b, h_bf);
  for (int b = 0; b < 2; ++b)
    transpose_b2b<<<dim3(24, 256), tb, 0, stream>>>(
        h_bf + (size_t)b * 8192 * 768, hT + (size_t)b * 768 * 8192, 768, 8192);
  rowsum512<<<128, 256, 0, stream>>>(EkT, colsum);
  // 3) q = h @ Wq + bq   (only q slice of qkv needed now)
  gemm128<true, true, false, false><<<dim3(128, 6), 256, 0, stream>>>(
      h_bf, qkv_wT, q_bf, qkv_b, nullptr, 768, 768, 768, 768);
  // 4) hkv[b] = [Ek;Ev]^T @ h[b]  : NT, split-K 4 -> fp32 partials -> bf16
  gemm_nt<64, 64, false, false, false, false, false><<<dim3(8, 12, 8), 256, 0, stream>>>(
      EkT, hT, part, nullptr, nullptr, nullptr, 2048, 8192, 8192, 768,
      4, 0, 2048, 768ull * 8192, 2048, 393216, 786432, 0, 0);
  kv_reduce<<<3072, 256, 0, stream>>>(part, hkv_bf);
  // 5) kv_proj[kvb] = hkv[b,half] @ W{k,v} + colsumE * bias  (associativity)
  gemm_nt<64, 64, true, true, false, false, true><<<dim3(4, 12, 4), 256, 0, stream>>>(
      hkv_bf, qkv_wT + 768ull * 768, kproj, qkv_b + 768, nullptr, colsum,
      768, 768, 768, 768,
      2, 512ull * 768, 256ull * 768, 0, 768ull * 768, 196608, 393216, 256, 768);
  // 6) v_projT[b] [768,256]
  for (int b = 0; b < 2; ++b)
    transpose_b2b<<<dim3(24, 8), tb, 0, stream>>>(
        kproj + (size_t)(2 + b) * 196608, vprojT + (size_t)b * 768 * 256, 768, 256);
  // 7) fused attention -> o_bf
  attn_fused<<<dim3(128, 24), 256, 0, stream>>>(q_bf, kproj, vprojT, o_bf);
  // 8) x2 = x + o @ proj_w + b -> d_out (fp32)
  gemm128<false, true, false, true><<<dim3(128, 6), 256, 0, stream>>>(
      o_bf, proj_wT, out, proj_b, x, 768, 768, 768, 768);
  // 9) LN2
  ln768<<<16384, 256, 0, stream>>>(out, ln2_w, ln2_b, h_bf);
  // 10) a1 = gelu(h2 @ fc1_w + b) -> big   (grid 64x24 = 1536 blocks)
  gemm256n<true, true, true, false><<<dim3(64, 24), 256, 0, stream>>>(
      h_bf, fc1_wT, big, fc1_b, nullptr, 768, 768, 768, 3072);
  // 11) out = x2 + a1 @ fc2_w + b (in-place residual)  (grid 64x6)
  gemm256n<false, true, false, true><<<dim3(64, 6), 256, 0, stream>>>(
      big, fc2_wT, out, fc2_b, out, 3072, 3072, 3072, 768);
}

// Round 8
// 467.072 us; speedup vs baseline: 1.1230x; 1.0133x over previous
//
#include <hip/hip_runtime.h>
#include <cstdint>

#define DEV __device__ __forceinline__

typedef __bf16 bf16x8 __attribute__((ext_vector_type(8)));
typedef float f32x4 __attribute__((ext_vector_type(4)));

DEV uint16_t f2bf(float f) {
  uint32_t u = __float_as_uint(f);
  u += 0x7FFFu + ((u >> 16) & 1u);
  return (uint16_t)(u >> 16);
}
DEV float bf2f(uint16_t h) { return __uint_as_float(((uint32_t)h) << 16); }

DEV void gload16(const void* g, void* l) {
  __builtin_amdgcn_global_load_lds((const __attribute__((address_space(1))) void*)g,
                                   (__attribute__((address_space(3))) void*)l, 16, 0, 0);
}

template <int N> DEV void waitcnt_vm() {
  if constexpr (N == 0) asm volatile("s_waitcnt vmcnt(0)" ::: "memory");
  else if constexpr (N == 3) asm volatile("s_waitcnt vmcnt(3)" ::: "memory");
  else if constexpr (N == 4) asm volatile("s_waitcnt vmcnt(4)" ::: "memory");
  else static_assert(N == 0 || N == 3 || N == 4, "unsupported vmcnt");
}

// fast GELU (tanh form): max abs err vs erf-GELU ~3e-3
DEV float gelu_f(float v) {
  float u = v * (0.7978845608f + 0.0356774081f * v * v);
  return v / (1.f + __expf(-2.f * u));
}

// ---------------- LayerNorm over C=768, fp32 in -> bf16 out ----------------
__global__ __launch_bounds__(256) void ln768(const float* __restrict__ x,
                                             const float* __restrict__ w,
                                             const float* __restrict__ b,
                                             uint16_t* __restrict__ out) {
  const size_t row = blockIdx.x;
  const float* xr = x + row * 768;
  const int t = threadIdx.x;
  float v0 = xr[t], v1 = xr[t + 256], v2 = xr[t + 512];
  float s = v0 + v1 + v2;
  float s2 = v0 * v0 + v1 * v1 + v2 * v2;
#pragma unroll
  for (int o = 32; o; o >>= 1) {
    s += __shfl_down(s, o);
    s2 += __shfl_down(s2, o);
  }
  __shared__ float sh[8];
  if ((t & 63) == 0) { sh[t >> 6] = s; sh[4 + (t >> 6)] = s2; }
  __syncthreads();
  s = sh[0] + sh[1] + sh[2] + sh[3];
  s2 = sh[4] + sh[5] + sh[6] + sh[7];
  const float mu = s * (1.f / 768.f);
  const float var = s2 * (1.f / 768.f) - mu * mu;
  const float rstd = rsqrtf(var + 1e-6f);
  uint16_t* orow = out + row * 768;
  orow[t]       = f2bf((v0 - mu) * rstd * w[t] + b[t]);
  orow[t + 256] = f2bf((v1 - mu) * rstd * w[t + 256] + b[t + 256]);
  orow[t + 512] = f2bf((v2 - mu) * rstd * w[t + 512] + b[t + 512]);
}

// ---------------- transpose fp32 [R,Cc] -> bf16 [Cc,R] ----------------
__global__ __launch_bounds__(256) void transpose_f2b(const float* __restrict__ in,
                                                     uint16_t* __restrict__ outp,
                                                     int ldin, int ldout) {
  __shared__ float tile[32][33];
  const int tx = threadIdx.x, ty = threadIdx.y;
  const size_t x = (size_t)blockIdx.x * 32 + tx;
  const size_t y = (size_t)blockIdx.y * 32 + ty;
#pragma unroll
  for (int j = 0; j < 4; ++j) tile[ty + j * 8][tx] = in[(y + j * 8) * ldin + x];
  __syncthreads();
  const size_t x2 = (size_t)blockIdx.y * 32 + tx;
  const size_t y2 = (size_t)blockIdx.x * 32 + ty;
#pragma unroll
  for (int j = 0; j < 4; ++j) outp[(y2 + j * 8) * ldout + x2] = f2bf(tile[tx][ty + j * 8]);
}

// -------- rowsum of EKV_T [512][8192] bf16 -> colsum[512] fp32 --------
__global__ __launch_bounds__(256) void rowsum512(const uint16_t* __restrict__ ekv,
                                                 float* __restrict__ colsum) {
  const int row = blockIdx.x * 4 + (threadIdx.x >> 6);
  const int lane = threadIdx.x & 63;
  const uint16_t* r = ekv + (size_t)row * 8192 + lane * 8;
  float s = 0.f;
#pragma unroll
  for (int it = 0; it < 16; ++it) {
    bf16x8 v = *(const bf16x8*)(r + it * 512);
#pragma unroll
    for (int j = 0; j < 8; ++j) s += (float)v[j];
  }
#pragma unroll
  for (int o = 32; o; o >>= 1) s += __shfl_down(s, o);
  if (lane == 0) colsum[row] = s;
}

// ======== hkv gather TN: part[ns][b][k][c] = sum_{n in stripe} E[n,k] h[b][n,c]
// E^T = [EkT;EvT] [512][8192] (contiguous); h [2][8192][768]. 768 blocks.
__global__ __launch_bounds__(256) void hkv_tn(const uint16_t* __restrict__ ET,
                                              const uint16_t* __restrict__ h,
                                              float* __restrict__ part) {
  const int bid = blockIdx.x;
  const int wg = (bid & 7) * 96 + (bid >> 3);
  const int inner = wg & 31;
  const int kt = inner & 7, ns = inner >> 3;  // kt in [0,8), ns in [0,4)
  const int rest = wg >> 5;                   // [0,24)
  const int ct = rest % 12, b = rest / 12;
  const int k0 = kt * 64, c0 = ct * 64, nsb = ns * 2048;

  const int tid = threadIdx.x, wave = tid >> 6, lane = tid & 63;
  const int l16 = lane & 15, lhi = lane >> 4;
  const int wm = wave >> 1, wn = wave & 1;

  f32x4 acc[2][2];
#pragma unroll
  for (int m = 0; m < 2; ++m)
#pragma unroll
    for (int n = 0; n < 2; ++n) acc[m][n] = f32x4{0.f, 0.f, 0.f, 0.f};

  const uint16_t* Eb = ET + (size_t)(k0 + wm * 32 + l16) * 8192 + nsb + lhi * 8;
  const uint16_t* Hb = h + ((size_t)b * 8192 + nsb + lhi * 8) * 768 + c0 + wn * 32 + l16;

  for (int n0 = 0; n0 < 2048; n0 += 32) {
    bf16x8 ef[2];
    ef[0] = *(const bf16x8*)(Eb + n0);
    ef[1] = *(const bf16x8*)(Eb + 16 * 8192 + n0);
    bf16x8 vf[2];
#pragma unroll
    for (int nf = 0; nf < 2; ++nf) {
      const uint16_t* p = Hb + (size_t)n0 * 768 + nf * 16;
      union { bf16x8 v; uint16_t u[8]; } tu;
#pragma unroll
      for (int j = 0; j < 8; ++j) tu.u[j] = p[(size_t)j * 768];
      vf[nf] = tu.v;
    }
#pragma unroll
    for (int m = 0; m < 2; ++m)
#pragma unroll
      for (int nf = 0; nf < 2; ++nf)
        acc[m][nf] = __builtin_amdgcn_mfma_f32_16x16x32_bf16(ef[m], vf[nf], acc[m][nf], 0, 0, 0);
  }

  float* outp = part + ((size_t)ns * 2 + b) * 393216;
#pragma unroll
  for (int m = 0; m < 2; ++m)
#pragma unroll
    for (int nf = 0; nf < 2; ++nf)
#pragma unroll
      for (int r = 0; r < 4; ++r)
        outp[(size_t)(k0 + wm * 32 + m * 16 + lhi * 4 + r) * 768 + c0 + wn * 32 + nf * 16 + l16] =
            acc[m][nf][r];
}

// -------- reduce 4 n-stripe fp32 partials -> bf16 hkv [b][512][768]
__global__ __launch_bounds__(256) void kv_reduce(const float* __restrict__ part,
                                                 uint16_t* __restrict__ hkv) {
  const int i = blockIdx.x * 256 + threadIdx.x;  // [0, 786432)
  float s = part[i] + part[786432 + i] + part[2 * 786432 + i] + part[3 * 786432 + i];
  hkv[i] = f2bf(s);
}

// ---------------- small NT GEMM with z-batching (kvW step) ----------
// C = A @ B^T + rowscale[row]*bias[col]; v-half (zlo==1) written transposed
// into vpt [b][768][256] instead of C.
template <int BM, int BN>
__global__ __launch_bounds__(256) void gemm_kvw(
    const uint16_t* __restrict__ Abase, const uint16_t* __restrict__ Bbase,
    uint16_t* __restrict__ Cbase, const float* __restrict__ bias,
    const float* __restrict__ rowscale, uint16_t* __restrict__ vpt,
    int Kd, int lda, int ldb, int ldc,
    int zdiv, size_t sAhi, size_t sAlo, size_t sBhi, size_t sBlo,
    size_t sChi, size_t sClo, int rs_z, int bias_z) {
  const int z = blockIdx.z;
  const int zhi = z / zdiv, zlo = z - zhi * zdiv;
  const uint16_t* A = Abase + zhi * sAhi + zlo * sAlo;
  const uint16_t* B = Bbase + zhi * sBhi + zlo * sBlo;
  const size_t coff = zhi * sChi + zlo * sClo;

  constexpr int WTM = BM / 2, WTN = BN / 2;
  constexpr int FM = WTM / 16, FN = WTN / 16;
  const int tid = threadIdx.x;
  const int wave = tid >> 6, lane = tid & 63;
  const int wm = wave >> 1, wn = wave & 1;
  const int l16 = lane & 15, lhi = lane >> 4;

  __shared__ __align__(16) uint16_t sA[BM * 32];
  __shared__ __align__(16) uint16_t sB[BN * 32];

  f32x4 acc[FM][FN];
#pragma unroll
  for (int m = 0; m < FM; ++m)
#pragma unroll
    for (int n = 0; n < FN; ++n) acc[m][n] = f32x4{0.f, 0.f, 0.f, 0.f};

  const int row0 = blockIdx.x * BM;
  const int col0 = blockIdx.y * BN;
  const int rr = tid >> 2, cq = tid & 3;

  for (int k0 = 0; k0 < Kd; k0 += 32) {
    __syncthreads();
#pragma unroll
    for (int is = 0; is < BM / 64; ++is) {
      const uint16_t* g = A + (size_t)(row0 + is * 64 + rr) * lda + k0 + cq * 8;
      gload16(g, &sA[is * 2048 + tid * 8]);
    }
#pragma unroll
    for (int is = 0; is < BN / 64; ++is) {
      const uint16_t* g = B + (size_t)(col0 + is * 64 + rr) * ldb + k0 + cq * 8;
      gload16(g, &sB[is * 2048 + tid * 8]);
    }
    __syncthreads();

    bf16x8 af[FM], bq[FN];
#pragma unroll
    for (int m = 0; m < FM; ++m)
      af[m] = *(const bf16x8*)(&sA[(wm * WTM + m * 16 + l16) * 32 + lhi * 8]);
#pragma unroll
    for (int n = 0; n < FN; ++n)
      bq[n] = *(const bf16x8*)(&sB[(wn * WTN + n * 16 + l16) * 32 + lhi * 8]);
#pragma unroll
    for (int m = 0; m < FM; ++m)
#pragma unroll
      for (int n = 0; n < FN; ++n)
        acc[m][n] = __builtin_amdgcn_mfma_f32_16x16x32_bf16(af[m], bq[n], acc[m][n], 0, 0, 0);
  }

#pragma unroll
  for (int m = 0; m < FM; ++m) {
#pragma unroll
    for (int n = 0; n < FN; ++n) {
      const int col = col0 + wn * WTN + n * 16 + l16;
      const float bv = bias[zlo * bias_z + col];
#pragma unroll
      for (int r = 0; r < 4; ++r) {
        const int row = row0 + wm * WTM + m * 16 + lhi * 4 + r;
        float v = acc[m][n][r] + rowscale[zlo * rs_z + row] * bv;
        if (zlo == 1) {
          // v_proj -> transposed store [b][c=col][k=row]
          vpt[(size_t)zhi * 196608 + (size_t)col * 256 + row] = f2bf(v);
        } else {
          Cbase[coff + (size_t)row * ldc + col] = f2bf(v);
        }
      }
    }
  }
}

// ======== fused attention: one (qtile64, b, h) block ========
__global__ __launch_bounds__(256, 3) void attn_fused(
    const uint16_t* __restrict__ q,      // [2][8192][768]
    const uint16_t* __restrict__ kproj,  // [2][256][768] (k only)
    const uint16_t* __restrict__ vprojT, // [2][768][256]
    uint16_t* __restrict__ o) {          // [2][8192][768]
  const int bh = blockIdx.y;
  const int b = bh / 12, h = bh % 12;
  const int n0 = blockIdx.x * 64;
  const int tid = threadIdx.x, wave = tid >> 6, lane = tid & 63;
  const int l16 = lane & 15, lhi = lane >> 4;
  const int wm = wave >> 1, wn = wave & 1;

  __shared__ __align__(16) uint16_t sP[64 * 256];
  __shared__ float redm[2][64], reds[2][64], recs[64];

  const uint16_t* Kp = kproj + (size_t)b * 196608 + h * 64;
  const uint16_t* Qp = q + ((size_t)b * 8192 + n0) * 768 + h * 64;
  const uint16_t* Vp = vprojT + ((size_t)b * 768 + h * 64) * 256;

  f32x4 st[8][2];
#pragma unroll
  for (int m = 0; m < 8; ++m)
#pragma unroll
    for (int nf = 0; nf < 2; ++nf) st[m][nf] = f32x4{0.f, 0.f, 0.f, 0.f};
#pragma unroll
  for (int ks = 0; ks < 2; ++ks) {
    bf16x8 kf[8], qf[2];
#pragma unroll
    for (int m = 0; m < 8; ++m) {
      const int kvi = wm * 128 + m * 16 + l16;
      kf[m] = *(const bf16x8*)(Kp + (size_t)kvi * 768 + ks * 32 + lhi * 8);
    }
#pragma unroll
    for (int nf = 0; nf < 2; ++nf) {
      const int n = wn * 32 + nf * 16 + l16;
      qf[nf] = *(const bf16x8*)(Qp + (size_t)n * 768 + ks * 32 + lhi * 8);
    }
#pragma unroll
    for (int m = 0; m < 8; ++m)
#pragma unroll
      for (int nf = 0; nf < 2; ++nf)
        st[m][nf] = __builtin_amdgcn_mfma_f32_16x16x32_bf16(kf[m], qf[nf], st[m][nf], 0, 0, 0);
  }

  float pmax[2] = {-50.f, -50.f};
#pragma unroll
  for (int m = 0; m < 8; ++m)
#pragma unroll
    for (int nf = 0; nf < 2; ++nf)
#pragma unroll
      for (int r = 0; r < 4; ++r) {
        float v = fminf(fmaxf(st[m][nf][r] * 0.125f, -50.f), 50.f);
        st[m][nf][r] = v;
        pmax[nf] = fmaxf(pmax[nf], v);
      }
#pragma unroll
  for (int nf = 0; nf < 2; ++nf) {
    pmax[nf] = fmaxf(pmax[nf], __shfl_xor(pmax[nf], 16));
    pmax[nf] = fmaxf(pmax[nf], __shfl_xor(pmax[nf], 32));
  }
  if (lhi == 0) {
#pragma unroll
    for (int nf = 0; nf < 2; ++nf) redm[wm][wn * 32 + nf * 16 + l16] = pmax[nf];
  }
  __syncthreads();
  float M[2];
#pragma unroll
  for (int nf = 0; nf < 2; ++nf) {
    const int col = wn * 32 + nf * 16 + l16;
    M[nf] = fmaxf(redm[0][col], redm[1][col]);
  }

  float psum[2] = {0.f, 0.f};
#pragma unroll
  for (int m = 0; m < 8; ++m) {
#pragma unroll
    for (int nf = 0; nf < 2; ++nf) {
      float e0 = __expf(st[m][nf][0] - M[nf]);
      float e1 = __expf(st[m][nf][1] - M[nf]);
      float e2 = __expf(st[m][nf][2] - M[nf]);
      float e3 = __expf(st[m][nf][3] - M[nf]);
      psum[nf] += (e0 + e1) + (e2 + e3);
      uint2 pk;
      pk.x = (uint32_t)f2bf(e0) | ((uint32_t)f2bf(e1) << 16);
      pk.y = (uint32_t)f2bf(e2) | ((uint32_t)f2bf(e3) << 16);
      const int n = wn * 32 + nf * 16 + l16;
      const int kvb2 = (wm * 128 + m * 16 + lhi * 4) * 2;
      *(uint2*)((char*)sP + n * 512 + (kvb2 ^ ((n & 7) << 4))) = pk;
    }
  }
#pragma unroll
  for (int nf = 0; nf < 2; ++nf) {
    psum[nf] += __shfl_xor(psum[nf], 16);
    psum[nf] += __shfl_xor(psum[nf], 32);
  }
  if (lhi == 0) {
#pragma unroll
    for (int nf = 0; nf < 2; ++nf) reds[wm][wn * 32 + nf * 16 + l16] = psum[nf];
  }
  __syncthreads();
  if (wm == 0 && lhi == 0) {
#pragma unroll
    for (int nf = 0; nf < 2; ++nf) {
      const int col = wn * 32 + nf * 16 + l16;
      recs[col] = 1.f / (reds[0][col] + reds[1][col]);
    }
  }
  __syncthreads();

  f32x4 pacc[2][2];
#pragma unroll
  for (int mf = 0; mf < 2; ++mf)
#pragma unroll
    for (int nf = 0; nf < 2; ++nf) pacc[mf][nf] = f32x4{0.f, 0.f, 0.f, 0.f};
#pragma unroll
  for (int ks = 0; ks < 8; ++ks) {
    bf16x8 pa[2], vb[2];
#pragma unroll
    for (int mf = 0; mf < 2; ++mf) {
      const int n = wm * 32 + mf * 16 + l16;
      pa[mf] = *(const bf16x8*)((char*)sP + n * 512 + ((ks * 64 + lhi * 16) ^ ((n & 7) << 4)));
    }
#pragma unroll
    for (int nf = 0; nf < 2; ++nf) {
      const int d = wn * 32 + nf * 16 + l16;
      vb[nf] = *(const bf16x8*)(Vp + (size_t)d * 256 + ks * 32 + lhi * 8);
    }
#pragma unroll
    for (int mf = 0; mf < 2; ++mf)
#pragma unroll
      for (int nf = 0; nf < 2; ++nf)
        pacc[mf][nf] = __builtin_amdgcn_mfma_f32_16x16x32_bf16(pa[mf], vb[nf], pacc[mf][nf], 0, 0, 0);
  }
  uint16_t* orow = o + ((size_t)b * 8192 + n0) * 768 + h * 64;
#pragma unroll
  for (int mf = 0; mf < 2; ++mf) {
#pragma unroll
    for (int r = 0; r < 4; ++r) {
      const int n = wm * 32 + mf * 16 + lhi * 4 + r;
      const float inv = recs[n];
#pragma unroll
      for (int nf = 0; nf < 2; ++nf) {
        const int d = wn * 32 + nf * 16 + l16;
        orow[(size_t)n * 768 + d] = f2bf(pacc[mf][nf][r] * inv);
      }
    }
  }
}

// ======== gemm128: 128x128 NT, BK=32, 3 bufs (48 KB), 3 blocks/CU ========
template <bool OUTBF, bool HASBIAS, bool DOGELU, bool HASRES>
__global__ __launch_bounds__(256, 3) void gemm128(
    const uint16_t* __restrict__ A, const uint16_t* __restrict__ B,
    void* __restrict__ Cbase, const float* __restrict__ bias,
    const float* __restrict__ res, int Kd, int lda, int ldb, int ldc) {
  constexpr int PL = 4096;
  __shared__ __align__(16) uint16_t lds[3 * 2 * PL];

  const int nn = gridDim.y;
  const int nwg = gridDim.x * gridDim.y;
  const int bid = blockIdx.y * gridDim.x + blockIdx.x;
  const int q = nwg >> 3, r8 = nwg & 7, xcd = bid & 7, idx = bid >> 3;
  const int wg = (xcd < r8 ? xcd * (q + 1) : r8 * (q + 1) + (xcd - r8) * q) + idx;
  const int bm = wg / nn, bn = wg % nn;
  const int row0 = bm * 128, col0 = bn * 128;

  const int tid = threadIdx.x;
  const int wave = tid >> 6, lane = tid & 63;
  const int wm = wave >> 1, wn = wave & 1;
  const int l16 = lane & 15, lhi = lane >> 4;
  const int srow = tid >> 2, sq = tid & 3;

  auto stage = [&](int buf, int t) {
    const int k0 = t * 32;
    uint16_t* sa = lds + buf * 2 * PL;
#pragma unroll
    for (int j = 0; j < 2; ++j) {
      const int rw = j * 64 + srow;
      const int sl = sq ^ ((rw >> 1) & 3);
      gload16(A + (size_t)(row0 + rw) * lda + k0 + sl * 8, sa + rw * 32 + sq * 8);
    }
#pragma unroll
    for (int j = 0; j < 2; ++j) {
      const int rw = j * 64 + srow;
      const int sl = sq ^ ((rw >> 1) & 3);
      gload16(B + (size_t)(col0 + rw) * ldb + k0 + sl * 8, sa + PL + rw * 32 + sq * 8);
    }
  };

  f32x4 acc[4][4];
#pragma unroll
  for (int m = 0; m < 4; ++m)
#pragma unroll
    for (int n = 0; n < 4; ++n) acc[m][n] = f32x4{0.f, 0.f, 0.f, 0.f};

  const int NT = Kd >> 5;
  stage(0, 0);
  stage(1, 1);

  for (int t = 0; t < NT; ++t) {
    if (t < NT - 1) waitcnt_vm<4>();
    else waitcnt_vm<0>();
    __builtin_amdgcn_s_barrier();
    asm volatile("" ::: "memory");
    if (t + 2 < NT) stage((t + 2) % 3, t + 2);

    const uint16_t* sa = lds + (t % 3) * 2 * PL;
    const uint16_t* sb = sa + PL;
    bf16x8 af[4], bfv[4];
#pragma unroll
    for (int n = 0; n < 4; ++n) {
      const int rw = wn * 64 + n * 16 + l16;
      bfv[n] = *(const bf16x8*)(sb + rw * 32 + (lhi ^ ((rw >> 1) & 3)) * 8);
    }
#pragma unroll
    for (int m = 0; m < 4; ++m) {
      const int rw = wm * 64 + m * 16 + l16;
      af[m] = *(const bf16x8*)(sa + rw * 32 + (lhi ^ ((rw >> 1) & 3)) * 8);
    }
    __builtin_amdgcn_s_setprio(1);
#pragma unroll
    for (int m = 0; m < 4; ++m)
#pragma unroll
      for (int n = 0; n < 4; ++n)
        acc[m][n] = __builtin_amdgcn_mfma_f32_16x16x32_bf16(af[m], bfv[n], acc[m][n], 0, 0, 0);
    __builtin_amdgcn_s_setprio(0);
  }

  float* Cf = (float*)Cbase;
  uint16_t* Cb = (uint16_t*)Cbase;
#pragma unroll
  for (int m = 0; m < 4; ++m) {
#pragma unroll
    for (int n = 0; n < 4; ++n) {
      const int col = col0 + wn * 64 + n * 16 + l16;
      float bv = 0.f;
      if (HASBIAS) bv = bias[col];
#pragma unroll
      for (int r = 0; r < 4; ++r) {
        const int row = row0 + wm * 64 + m * 16 + lhi * 4 + r;
        float v = acc[m][n][r] + bv;
        if (DOGELU) v = gelu_f(v);
        const size_t cidx = (size_t)row * ldc + col;
        if (HASRES) v += res[cidx];
        if (OUTBF) Cb[cidx] = f2bf(v);
        else Cf[cidx] = v;
      }
    }
  }
}

// ======== gemm512: 256x128 NT, 512 thr / 8 waves (4x2), wave-tile 64x64,
// BK=32, 3 bufs (72 KB), 2 blocks/CU, counted vmcnt(3).  (round-3 winner) ====
template <bool OUTBF, bool HASBIAS, bool DOGELU, bool HASRES>
__global__ __launch_bounds__(512, 4) void gemm512(
    const uint16_t* __restrict__ A, const uint16_t* __restrict__ B,
    void* __restrict__ Cbase, const float* __restrict__ bias,
    const float* __restrict__ res, int Kd, int lda, int ldb, int ldc) {
  constexpr int APL = 8192, BPL = 4096;
  __shared__ __align__(16) uint16_t lds[3 * (APL + BPL)];  // 72 KB

  const int nn = gridDim.y;
  const int nwg = gridDim.x * gridDim.y;
  const int bid = blockIdx.y * gridDim.x + blockIdx.x;
  const int q = nwg >> 3, r8 = nwg & 7, xcd = bid & 7, idx = bid >> 3;
  const int wg = (xcd < r8 ? xcd * (q + 1) : r8 * (q + 1) + (xcd - r8) * q) + idx;
  const int bm = wg / nn, bn = wg % nn;
  const int row0 = bm * 256, col0 = bn * 128;

  const int tid = threadIdx.x;
  const int wave = tid >> 6, lane = tid & 63;
  const int wm = wave >> 1, wn = wave & 1;  // 4 x 2
  const int l16 = lane & 15, lhi = lane >> 4;
  const int srow = tid >> 2, sq = tid & 3;  // 128 rows per inst

  auto stage = [&](int buf, int t) {
    const int k0 = t * 32;
    uint16_t* sa = lds + buf * (APL + BPL);
#pragma unroll
    for (int j = 0; j < 2; ++j) {
      const int rw = j * 128 + srow;
      const int sl = sq ^ ((rw >> 1) & 3);
      gload16(A + (size_t)(row0 + rw) * lda + k0 + sl * 8, sa + rw * 32 + sq * 8);
    }
    {
      const int rw = srow;
      const int sl = sq ^ ((rw >> 1) & 3);
      gload16(B + (size_t)(col0 + rw) * ldb + k0 + sl * 8, sa + APL + rw * 32 + sq * 8);
    }
  };

  f32x4 acc[4][4];
#pragma unroll
  for (int m = 0; m < 4; ++m)
#pragma unroll
    for (int n = 0; n < 4; ++n) acc[m][n] = f32x4{0.f, 0.f, 0.f, 0.f};

  const int NT = Kd >> 5;
  stage(0, 0);
  stage(1, 1);

  for (int t = 0; t < NT; ++t) {
    if (t < NT - 1) waitcnt_vm<3>();
    else waitcnt_vm<0>();
    __builtin_amdgcn_s_barrier();
    asm volatile("" ::: "memory");
    if (t + 2 < NT) stage((t + 2) % 3, t + 2);

    const uint16_t* sa = lds + (t % 3) * (APL + BPL);
    const uint16_t* sb = sa + APL;
    bf16x8 af[4], bfv[4];
#pragma unroll
    for (int n = 0; n < 4; ++n) {
      const int rw = wn * 64 + n * 16 + l16;
      bfv[n] = *(const bf16x8*)(sb + rw * 32 + (lhi ^ ((rw >> 1) & 3)) * 8);
    }
#pragma unroll
    for (int m = 0; m < 4; ++m) {
      const int rw = wm * 64 + m * 16 + l16;
      af[m] = *(const bf16x8*)(sa + rw * 32 + (lhi ^ ((rw >> 1) & 3)) * 8);
    }
    __builtin_amdgcn_s_setprio(1);
#pragma unroll
    for (int m = 0; m < 4; ++m)
#pragma unroll
      for (int n = 0; n < 4; ++n)
        acc[m][n] = __builtin_amdgcn_mfma_f32_16x16x32_bf16(af[m], bfv[n], acc[m][n], 0, 0, 0);
    __builtin_amdgcn_s_setprio(0);
  }

  float* Cf = (float*)Cbase;
  uint16_t* Cb = (uint16_t*)Cbase;
#pragma unroll
  for (int m = 0; m < 4; ++m) {
#pragma unroll
    for (int n = 0; n < 4; ++n) {
      const int col = col0 + wn * 64 + n * 16 + l16;
      float bv = 0.f;
      if (HASBIAS) bv = bias[col];
#pragma unroll
      for (int r = 0; r < 4; ++r) {
        const int row = row0 + wm * 64 + m * 16 + lhi * 4 + r;
        float v = acc[m][n][r] + bv;
        if (DOGELU) v = gelu_f(v);
        const size_t cidx = (size_t)row * ldc + col;
        if (HASRES) v += res[cidx];
        if (OUTBF) Cb[cidx] = f2bf(v);
        else Cf[cidx] = v;
      }
    }
  }
}

extern "C" void kernel_launch(void* const* d_in, const int* in_sizes, int n_in,
                              void* d_out, int out_size, void* d_ws, size_t ws_size,
                              hipStream_t stream) {
  const float* x      = (const float*)d_in[0];
  const float* ln1_w  = (const float*)d_in[1];
  const float* ln1_b  = (const float*)d_in[2];
  const float* qkv_w  = (const float*)d_in[3];
  const float* qkv_b  = (const float*)d_in[4];
  const float* Ek     = (const float*)d_in[5];
  const float* Ev     = (const float*)d_in[6];
  const float* proj_w = (const float*)d_in[7];
  const float* proj_b = (const float*)d_in[8];
  const float* ln2_w  = (const float*)d_in[9];
  const float* ln2_b  = (const float*)d_in[10];
  const float* fc1_w  = (const float*)d_in[11];
  const float* fc1_b  = (const float*)d_in[12];
  const float* fc2_w  = (const float*)d_in[13];
  const float* fc2_b  = (const float*)d_in[14];
  float* out = (float*)d_out;

  char* w8 = (char*)d_ws;
  size_t off = 0;
  auto take = [&](size_t bytes) { char* p = w8 + off; off += bytes; return p; };
  uint16_t* qkv_wT  = (uint16_t*)take(2304ull * 768 * 2);
  uint16_t* proj_wT = (uint16_t*)take(768ull * 768 * 2);
  uint16_t* fc1_wT  = (uint16_t*)take(3072ull * 768 * 2);
  uint16_t* fc2_wT  = (uint16_t*)take(768ull * 3072 * 2);
  uint16_t* EkT     = (uint16_t*)take(256ull * 8192 * 2);   // ET rows 0-255
  uint16_t* EvT     = (uint16_t*)take(256ull * 8192 * 2);   // ET rows 256-511 (contiguous)
  uint16_t* h_bf    = (uint16_t*)take(16384ull * 768 * 2);
  uint16_t* q_bf    = (uint16_t*)take(16384ull * 768 * 2);
  uint16_t* big     = (uint16_t*)take(100663296ull);           // hkv partials -> fc1 out
  uint16_t* hkv_bf  = (uint16_t*)take(2ull * 512 * 768 * 2);   // [b][512][768]
  uint16_t* kproj   = (uint16_t*)take(2ull * 256 * 768 * 2);   // [b][256][768] (k only)
  uint16_t* vprojT  = (uint16_t*)take(2ull * 768 * 256 * 2);   // [b][768][256]
  uint16_t* o_bf    = (uint16_t*)take(16384ull * 768 * 2);
  float* colsum     = (float*)take(512 * 4);
  float* part = (float*)big;  // [4][2][512][768] fp32 = 12.6 MB
  (void)ws_size; (void)in_sizes; (void)n_in; (void)out_size;

  const dim3 tb(32, 8);
  // 1) weights / projections -> bf16 transposed
  transpose_f2b<<<dim3(72, 24), tb, 0, stream>>>(qkv_w, qkv_wT, 2304, 768);
  transpose_f2b<<<dim3(24, 24), tb, 0, stream>>>(proj_w, proj_wT, 768, 768);
  transpose_f2b<<<dim3(96, 24), tb, 0, stream>>>(fc1_w, fc1_wT, 3072, 768);
  transpose_f2b<<<dim3(24, 96), tb, 0, stream>>>(fc2_w, fc2_wT, 768, 3072);
  transpose_f2b<<<dim3(8, 256), tb, 0, stream>>>(Ek, EkT, 256, 8192);
  transpose_f2b<<<dim3(8, 256), tb, 0, stream>>>(Ev, EvT, 256, 8192);
  rowsum512<<<128, 256, 0, stream>>>(EkT, colsum);
  // 2) LN1 -> h_bf
  ln768<<<16384, 256, 0, stream>>>(x, ln1_w, ln1_b, h_bf);
  // 3) q = h @ Wq + bq
  gemm128<true, true, false, false><<<dim3(128, 6), 256, 0, stream>>>(
      h_bf, qkv_wT, q_bf, qkv_b, nullptr, 768, 768, 768, 768);
  // 4) hkv = [Ek;Ev]^T @ h  (gather TN, 4 n-stripe partials) -> reduce
  hkv_tn<<<768, 256, 0, stream>>>(EkT, h_bf, part);
  kv_reduce<<<3072, 256, 0, stream>>>(part, hkv_bf);
  // 5) k_proj = hkv_k @ Wk + colsumEk*bk -> kproj; v_proj transposed -> vprojT
  gemm_kvw<64, 64><<<dim3(4, 12, 4), 256, 0, stream>>>(
      hkv_bf, qkv_wT + 768ull * 768, kproj, qkv_b + 768, colsum, vprojT,
      768, 768, 768, 768,
      2, 512ull * 768, 256ull * 768, 0, 768ull * 768, 196608, 0, 256, 768);
  // 6) fused attention -> o_bf
  attn_fused<<<dim3(128, 24), 256, 0, stream>>>(q_bf, kproj, vprojT, o_bf);
  // 7) x2 = x + o @ proj_w + b -> d_out (fp32)
  gemm128<false, true, false, true><<<dim3(128, 6), 256, 0, stream>>>(
      o_bf, proj_wT, out, proj_b, x, 768, 768, 768, 768);
  // 8) LN2
  ln768<<<16384, 256, 0, stream>>>(out, ln2_w, ln2_b, h_bf);
  // 9) a1 = gelu(h2 @ fc1_w + b) -> big   (gemm512: round-3 winner config)
  gemm512<true, true, true, false><<<dim3(64, 24), 512, 0, stream>>>(
      h_bf, fc1_wT, big, fc1_b, nullptr, 768, 768, 768, 3072);
  // 10) out = x2 + a1 @ fc2_w + b (in-place residual)
  gemm128<false, true, false, true><<<dim3(128, 6), 256, 0, stream>>>(
      big, fc2_wT, out, fc2_b, out, 3072, 3072, 3072, 768);
}